// Round 7
// baseline (198.245 us; speedup 1.0000x reference)
//
#include <hip/hip_runtime.h>
#include <math.h>

#define NTOT (128*128*128)
#define NBIN2 64                 // bins per axis (2 cells per bin)
#define BINS (NBIN2*NBIN2*NBIN2) // 262144
#define SCAN_BLOCKS 256

#define ZP 72                    // complex-mesh z pitch (>= 65, mult of 8)
#define RCAP 384                 // staged atoms per rho block (mean 165, +17 sigma)

#define PI_F      3.14159265358979323846f
#define TWO_PI_F  6.28318530717958647692f
#define FOUR_PI_F 12.5663706143591729539f

// ---------- helpers ----------

__device__ inline void inv3x3(const float* __restrict__ c, float* inv, float* detOut) {
    float a = c[0], b = c[1], cc = c[2];
    float d = c[3], e = c[4], f  = c[5];
    float g = c[6], h = c[7], i  = c[8];
    float A = e * i - f * h;
    float B = f * g - d * i;
    float C = d * h - e * g;
    float det = a * A + b * B + cc * C;
    float r = 1.0f / det;
    inv[0] = A * r;              inv[1] = (cc * h - b * i) * r;  inv[2] = (b * f - cc * e) * r;
    inv[3] = B * r;              inv[4] = (a * i - cc * g) * r;  inv[5] = (cc * d - a * f) * r;
    inv[6] = C * r;              inv[7] = (b * g - a * h) * r;   inv[8] = (a * e - b * d) * r;
    *detOut = det;
}

__device__ inline void w4(float x, float* w) {
    float x2 = x * x, x3 = x2 * x;
    w[0] = (1.0f  - 6.0f  * x + 12.0f * x2 - 8.0f  * x3) * (1.0f / 48.0f);
    w[1] = (23.0f - 30.0f * x - 12.0f * x2 + 24.0f * x3) * (1.0f / 48.0f);
    w[2] = (23.0f + 30.0f * x - 12.0f * x2 - 24.0f * x3) * (1.0f / 48.0f);
    w[3] = (1.0f  + 6.0f  * x + 12.0f * x2 + 8.0f  * x3) * (1.0f / 48.0f);
}

__device__ inline void atom_rel(const float* __restrict__ cell,
                                const float* __restrict__ pos, int t,
                                float* rx, float* ry, float* rz) {
    float inv[9]; float det;
    inv3x3(cell, inv, &det);
    float px = pos[3 * t], py = pos[3 * t + 1], pz = pos[3 * t + 2];
    *rx = (px * inv[0] + py * inv[3] + pz * inv[6]) * 128.0f;
    *ry = (px * inv[1] + py * inv[4] + pz * inv[7]) * 128.0f;
    *rz = (px * inv[2] + py * inv[5] + pz * inv[8]) * 128.0f;
}

__device__ inline int bin_of(float rx, float ry, float rz) {
    int ix = ((int)floorf(rx)) & 127;
    int iy = ((int)floorf(ry)) & 127;
    int iz = ((int)floorf(rz)) & 127;
    return ((((ix >> 1) << 6) | (iy >> 1)) << 6) | (iz >> 1);
}

// ---------- binning (unchanged from round 6) ----------

__global__ void zero_int_kernel(int* __restrict__ p, int n) {
    int i = blockIdx.x * blockDim.x + threadIdx.x;
    if (i < n) p[i] = 0;
}

__global__ void hist_kernel(const float* __restrict__ cell, const float* __restrict__ pos,
                            int* __restrict__ hist, int n) {
    int t = blockIdx.x * blockDim.x + threadIdx.x;
    if (t >= n) return;
    float rx, ry, rz;
    atom_rel(cell, pos, t, &rx, &ry, &rz);
    atomicAdd(&hist[bin_of(rx, ry, rz)], 1);
}

__global__ __launch_bounds__(256) void scan_local(const int4* __restrict__ hist4,
                                                  int4* __restrict__ off4,
                                                  int* __restrict__ partials) {
    const int b = blockIdx.x, t = threadIdx.x;
    const int idx = b * 256 + t;
    int4 h = hist4[idx];
    int s = h.x + h.y + h.z + h.w;
    int lane = t & 63, wv = t >> 6;
    int v = s;
    #pragma unroll
    for (int d = 1; d < 64; d <<= 1) {
        int o = __shfl_up(v, d, 64);
        if (lane >= d) v += o;
    }
    __shared__ int wsum[4];
    if (lane == 63) wsum[wv] = v;
    __syncthreads();
    int add = 0;
    #pragma unroll
    for (int k = 0; k < 4; ++k) if (k < wv) add += wsum[k];
    int run = add + v - s;
    int4 o4;
    o4.x = run; run += h.x;
    o4.y = run; run += h.y;
    o4.z = run; run += h.z;
    o4.w = run; run += h.w;
    off4[idx] = o4;
    if (t == 255) partials[b] = run;
}

__global__ __launch_bounds__(256) void scan_add(int4* __restrict__ hist4,
                                                int4* __restrict__ off4,
                                                const int* __restrict__ partials,
                                                int* __restrict__ offsets) {
    const int b = blockIdx.x, t = threadIdx.x;
    int lane = t & 63, wv = t >> 6;
    int v = (t < b) ? partials[t] : 0;
    #pragma unroll
    for (int d = 32; d >= 1; d >>= 1) v += __shfl_xor(v, d, 64);
    __shared__ int ws2[4];
    __shared__ int base_s;
    if (lane == 0) ws2[wv] = v;
    __syncthreads();
    if (t == 0) base_s = ws2[0] + ws2[1] + ws2[2] + ws2[3];
    __syncthreads();
    const int base = base_s;
    const int idx = b * 256 + t;
    int4 o4 = off4[idx];
    o4.x += base; o4.y += base; o4.z += base; o4.w += base;
    off4[idx]  = o4;
    hist4[idx] = o4;
    if (b == SCAN_BLOCKS - 1 && t == 255) offsets[BINS] = base + partials[b];
}

__global__ void reorder_kernel(const float* __restrict__ cell, const float* __restrict__ pos,
                               const float* __restrict__ q, int* __restrict__ cursor,
                               float4* __restrict__ sorted, int* __restrict__ sortedIdx, int n) {
    int t = blockIdx.x * blockDim.x + threadIdx.x;
    if (t >= n) return;
    float rx, ry, rz;
    atom_rel(cell, pos, t, &rx, &ry, &rz);
    int p = atomicAdd(&cursor[bin_of(rx, ry, rz)], 1);
    sorted[p] = make_float4(rx, ry, rz, q[t]);
    sortedIdx[p] = t;
}

// ---------- cell-centric rho: no atomics, no flat map ----------
// block = 8x8x8 cells; stages 6x6x6 bins with per-axis weights precomputed.

__global__ __launch_bounds__(512) void cell_rho_kernel(const float4* __restrict__ atoms,
                                                       const int* __restrict__ offsets,
                                                       float* __restrict__ rmesh) {
    const int blk = blockIdx.x;                  // 16x16x16 blocks
    const int bzb = blk & 15, byb = (blk >> 4) & 15, bxb = blk >> 8;
    const int cx0 = bxb << 3, cy0 = byb << 3, cz0 = bzb << 3;
    const int bx0 = (cx0 - 2) >> 1, by0 = (cy0 - 2) >> 1, bz0 = (cz0 - 2) >> 1;

    __shared__ float4 swx[RCAP], swy[RCAP], swz[RCAP], smeta[RCAP];
    __shared__ int binStart[217];
    __shared__ int gbase[216];
    __shared__ int wsum[4];

    const int t = threadIdx.x;
    int cnt = 0;
    if (t < 216) {
        int jx = t / 36, rr = t - jx * 36, jy = rr / 6, jz = rr - jy * 6;
        int bx = (bx0 + jx) & 63, by = (by0 + jy) & 63, bz = (bz0 + jz) & 63;
        int bin = (((bx << 6) | by) << 6) | bz;
        int g0 = offsets[bin];
        gbase[t] = g0;
        cnt = offsets[bin + 1] - g0;
    }
    // block scan over 216 counts (first 4 waves carry data)
    int v = cnt;
    {
        int lane = t & 63;
        #pragma unroll
        for (int d = 1; d < 64; d <<= 1) {
            int o = __shfl_up(v, d, 64);
            if (lane >= d) v += o;
        }
        if (lane == 63 && t < 256) wsum[t >> 6] = v;
    }
    __syncthreads();
    if (t < 216) {
        int add = 0;
        int wv = t >> 6;
        for (int k = 0; k < wv; ++k) add += wsum[k];
        binStart[t] = add + v - cnt;
        if (t == 215) binStart[216] = add + v;
    }
    __syncthreads();

    // stage atoms with precomputed per-axis weights
    if (t < 216) {
        int s0 = gbase[t] - gbase[t];             // dummy to keep regs tight
        s0 = binStart[t];
        int g0 = gbase[t];
        for (int k = 0; k < cnt; ++k) {
            int d = s0 + k;
            if (d >= RCAP) break;                 // statistically never
            float4 a = atoms[g0 + k];
            float w[4];
            float flx = floorf(a.x), fly = floorf(a.y), flz = floorf(a.z);
            w4(a.x - flx - 0.5f, w);
            swx[d] = make_float4(w[0], w[1], w[2], w[3]);
            w4(a.y - fly - 0.5f, w);
            swy[d] = make_float4(w[0], w[1], w[2], w[3]);
            w4(a.z - flz - 0.5f, w);
            swz[d] = make_float4(w[0], w[1], w[2], w[3]);
            smeta[d] = make_float4(flx, fly, flz, a.w);
        }
    }
    __syncthreads();

    const int lz = t & 7, ly = (t >> 3) & 7, lx = t >> 6;
    const int cx = cx0 + lx, cy = cy0 + ly, cz = cz0 + lz;
    const int jxlo = ((cx - 2) >> 1) - bx0, jxhi = ((cx + 1) >> 1) - bx0;
    const int jylo = ((cy - 2) >> 1) - by0, jyhi = ((cy + 1) >> 1) - by0;
    const int jzlo = ((cz - 2) >> 1) - bz0, jzhi = ((cz + 1) >> 1) - bz0;

    float acc = 0.0f;
    for (int jx = jxlo; jx <= jxhi; ++jx) {
        for (int jy = jylo; jy <= jyhi; ++jy) {
            int g = jx * 36 + jy * 6;
            int lo = binStart[g + jzlo];
            int hi = binStart[g + jzhi + 1];
            if (hi > RCAP) hi = RCAP;
            for (int i = lo; i < hi; ++i) {
                float4 m = smeta[i];
                int sx = (cx - (int)m.x + 1) & 127;
                int sy = (cy - (int)m.y + 1) & 127;
                int sz = (cz - (int)m.z + 1) & 127;
                float4 wx4 = swx[i];
                float4 wy4 = swy[i];
                float4 wz4 = swz[i];
                float wxv = sx == 0 ? wx4.x : sx == 1 ? wx4.y : sx == 2 ? wx4.z : sx == 3 ? wx4.w : 0.0f;
                float wyv = sy == 0 ? wy4.x : sy == 1 ? wy4.y : sy == 2 ? wy4.z : sy == 3 ? wy4.w : 0.0f;
                float wzv = sz == 0 ? wz4.x : sz == 1 ? wz4.y : sz == 2 ? wz4.z : sz == 3 ? wz4.w : 0.0f;
                acc += m.w * wxv * wyv * wzv;
            }
        }
    }
    rmesh[(cx << 14) | (cy << 7) | cz] = acc;
}

// ---------- register-shuffle 128-pt FFT (wave per line) ----------
// lane holds positions p0 = lane, p1 = lane + 64 (slot0/slot1).

__device__ inline void bfly_dif(float& rr, float& ii, int h, bool hi, float cs, float sn) {
    float pr = __shfl_xor(rr, h), pi = __shfl_xor(ii, h);
    float br = hi ? (pr - rr) : (rr + pr);
    float bi = hi ? (pi - ii) : (ii + pi);
    rr = cs * br - sn * bi;
    ii = cs * bi + sn * br;
}

__device__ inline void bfly_dit(float& rr, float& ii, int h, bool hi, float cs, float sn) {
    float pr = __shfl_xor(rr, h), pi = __shfl_xor(ii, h);
    float xr = hi ? rr : pr, xi = hi ? ii : pi;     // odd element (gets twiddle)
    float br = hi ? pr : rr, bi = hi ? pi : ii;     // even element
    float tr = cs * xr - sn * xi, ti = cs * xi + sn * xr;
    rr = hi ? (br - tr) : (br + tr);
    ii = hi ? (bi - ti) : (bi + ti);
}

// forward DIF: natural input -> storage (s,l) holds X[rev7(s*64+l)]
__device__ inline void wfft_dif_fwd(float& r0, float& i0, float& r1, float& i1, int lane) {
    {
        float ang = -PI_F * (float)lane * (1.0f / 64.0f);
        float sn, cs; __sincosf(ang, &sn, &cs);
        float ar = r0 + r1, ai = i0 + i1;
        float dr = r0 - r1, di = i0 - i1;
        r0 = ar; i0 = ai;
        r1 = cs * dr - sn * di;
        i1 = cs * di + sn * dr;
    }
    #pragma unroll
    for (int h = 32; h >= 1; h >>= 1) {
        int pos = lane & (h - 1);
        bool hi = (lane & h) != 0;
        float ang = hi ? (-PI_F * (float)pos / (float)h) : 0.0f;
        float sn, cs; __sincosf(ang, &sn, &cs);
        bfly_dif(r0, i0, h, hi, cs, sn);
        bfly_dif(r1, i1, h, hi, cs, sn);
    }
}

// inverse DIT: storage (s,l) holds bitrev-ordered input -> natural x[s*64+l]
__device__ inline void wfft_dit_inv(float& r0, float& i0, float& r1, float& i1, int lane) {
    #pragma unroll
    for (int h = 1; h <= 32; h <<= 1) {
        int pos = lane & (h - 1);
        bool hi = (lane & h) != 0;
        float ang = PI_F * (float)pos / (float)h;
        float sn, cs; __sincosf(ang, &sn, &cs);
        bfly_dit(r0, i0, h, hi, cs, sn);
        bfly_dit(r1, i1, h, hi, cs, sn);
    }
    {
        float ang = PI_F * (float)lane * (1.0f / 64.0f);
        float sn, cs; __sincosf(ang, &sn, &cs);
        float tr = cs * r1 - sn * i1, ti = cs * i1 + sn * r1;
        float nr = r0 + tr, ni = i0 + ti;
        r1 = r0 - tr; i1 = i0 - ti;
        r0 = nr; i0 = ni;
    }
}

// ---------- z forward: real -> complex natural order (Hermitian prefix) ----------

__global__ __launch_bounds__(1024) void fftZfwd(const float* __restrict__ rin,
                                                float2* __restrict__ mesh) {
    __shared__ float tre[16][132], tim[16][132];
    const int t = threadIdx.x, b = blockIdx.x;
    for (int u = t; u < 2048; u += 1024) {
        int l = u >> 7, e = u & 127;
        tre[l][e] = rin[((size_t)((b << 4) | l) << 7) + e];
    }
    __syncthreads();
    const int w = t >> 6, lane = t & 63;
    float r0 = tre[w][lane],      i0 = 0.0f;
    float r1 = tre[w][lane + 64], i1 = 0.0f;
    wfft_dif_fwd(r0, i0, r1, i1, lane);
    int e0 = (int)(__brev((unsigned)lane) >> 25);   // rev7(lane), even
    tre[w][e0] = r0;     tim[w][e0] = i0;
    tre[w][e0 + 1] = r1; tim[w][e0 + 1] = i1;       // rev7(lane+64) = e0+1
    __syncthreads();
    for (int u = t; u < 2048; u += 1024) {
        int l = u >> 7, e = u & 127;
        if (e < ZP)
            mesh[(size_t)((b << 4) | l) * ZP + e] = make_float2(tre[l][e], tim[l][e]);
    }
}

// ---------- y forward: natural in -> bit-reversed positions (stored in place) ----------

__global__ __launch_bounds__(512) void fftYfwd(float2* __restrict__ mesh) {
    __shared__ float tre[8][132], tim[8][132];
    const int t = threadIdx.x, b = blockIdx.x;
    const int x = b & 127, zf0 = (b >> 7) << 3;
    const size_t rb = ((size_t)(x << 7)) * ZP + zf0;
    for (int u = t; u < 1024; u += 512) {
        int e = u >> 3, dz = u & 7;
        float2 vv = mesh[rb + (size_t)e * ZP + dz];
        tre[dz][e] = vv.x; tim[dz][e] = vv.y;
    }
    __syncthreads();
    const int w = t >> 6, lane = t & 63;
    float r0 = tre[w][lane],      i0 = tim[w][lane];
    float r1 = tre[w][lane + 64], i1 = tim[w][lane + 64];
    wfft_dif_fwd(r0, i0, r1, i1, lane);
    tre[w][lane] = r0;      tim[w][lane] = i0;
    tre[w][lane + 64] = r1; tim[w][lane + 64] = i1;
    __syncthreads();
    for (int u = t; u < 1024; u += 512) {
        int e = u >> 3, dz = u & 7;
        mesh[rb + (size_t)e * ZP + dz] = make_float2(tre[dz][e], tim[dz][e]);
    }
}

// ---------- fused x: DIF fwd -> G(k) at rev-indexed k -> DIT inv ----------

__global__ __launch_bounds__(512) void fftXGw(float2* __restrict__ mesh,
                                              const float* __restrict__ cell) {
    __shared__ float tre[8][132], tim[8][132];
    const int t = threadIdx.x, b = blockIdx.x;
    const int py = b & 127, zf0 = (b >> 7) << 3;
    for (int u = t; u < 1024; u += 512) {
        int e = u >> 3, dz = u & 7;
        float2 vv = mesh[(size_t)((e << 7) | py) * ZP + zf0 + dz];
        tre[dz][e] = vv.x; tim[dz][e] = vv.y;
    }
    __syncthreads();
    const int w = t >> 6, lane = t & 63;
    float r0 = tre[w][lane],      i0 = tim[w][lane];
    float r1 = tre[w][lane + 64], i1 = tim[w][lane + 64];
    wfft_dif_fwd(r0, i0, r1, i1, lane);
    {
        float inv[9]; float det; inv3x3(cell, inv, &det);
        float invVol = 1.0f / fabsf(det);
        int my = (int)(__brev((unsigned)py) >> 25);
        int mz = zf0 + w;
        float fy = (my < 64) ? (float)my : (float)(my - 128);
        float fz = (mz < 64) ? (float)mz : (float)(mz - 128);
        int mx0 = (int)(__brev((unsigned)lane) >> 25);
        #pragma unroll
        for (int s = 0; s < 2; ++s) {
            int mx = mx0 + s;                      // rev7(lane+64) = mx0+1
            float fx = (mx < 64) ? (float)mx : (float)(mx - 128);
            float kx = TWO_PI_F * (fx * inv[0] + fy * inv[1] + fz * inv[2]);
            float ky = TWO_PI_F * (fx * inv[3] + fy * inv[4] + fz * inv[5]);
            float kz = TWO_PI_F * (fx * inv[6] + fy * inv[7] + fz * inv[8]);
            float ksq = kx * kx + ky * ky + kz * kz;
            float G = (ksq == 0.0f) ? 0.0f
                      : FOUR_PI_F / ksq * __expf(-0.5f * ksq) * invVol;
            if (s == 0) { r0 *= G; i0 *= G; } else { r1 *= G; i1 *= G; }
        }
    }
    wfft_dit_inv(r0, i0, r1, i1, lane);
    tre[w][lane] = r0;      tim[w][lane] = i0;
    tre[w][lane + 64] = r1; tim[w][lane + 64] = i1;
    __syncthreads();
    for (int u = t; u < 1024; u += 512) {
        int e = u >> 3, dz = u & 7;
        mesh[(size_t)((e << 7) | py) * ZP + zf0 + dz] =
            make_float2(tre[dz][e], tim[dz][e]);
    }
}

// ---------- y inverse: bit-reversed positions in -> natural out ----------

__global__ __launch_bounds__(512) void fftYinv(float2* __restrict__ mesh) {
    __shared__ float tre[8][132], tim[8][132];
    const int t = threadIdx.x, b = blockIdx.x;
    const int x = b & 127, zf0 = (b >> 7) << 3;
    const size_t rb = ((size_t)(x << 7)) * ZP + zf0;
    for (int u = t; u < 1024; u += 512) {
        int e = u >> 3, dz = u & 7;
        float2 vv = mesh[rb + (size_t)e * ZP + dz];
        tre[dz][e] = vv.x; tim[dz][e] = vv.y;
    }
    __syncthreads();
    const int w = t >> 6, lane = t & 63;
    float r0 = tre[w][lane],      i0 = tim[w][lane];
    float r1 = tre[w][lane + 64], i1 = tim[w][lane + 64];
    wfft_dit_inv(r0, i0, r1, i1, lane);
    tre[w][lane] = r0;      tim[w][lane] = i0;
    tre[w][lane + 64] = r1; tim[w][lane + 64] = i1;
    __syncthreads();
    for (int u = t; u < 1024; u += 512) {
        int e = u >> 3, dz = u & 7;
        mesh[rb + (size_t)e * ZP + dz] = make_float2(tre[dz][e], tim[dz][e]);
    }
}

// ---------- z inverse: Hermitian mirror, natural content -> real out ----------

__global__ __launch_bounds__(1024) void fftZinv(const float2* __restrict__ mesh,
                                                float* __restrict__ rout) {
    __shared__ float tre[16][132], tim[16][132];
    const int t = threadIdx.x, b = blockIdx.x;
    for (int u = t; u < 2048; u += 1024) {
        int l = u >> 7, e = u & 127;
        int src = (e <= 64) ? e : 128 - e;
        float2 vv = mesh[(size_t)((b << 4) | l) * ZP + src];
        tre[l][e] = vv.x;
        tim[l][e] = (e <= 64) ? vv.y : -vv.y;
    }
    __syncthreads();
    const int w = t >> 6, lane = t & 63;
    int e0 = (int)(__brev((unsigned)lane) >> 25);
    float r0 = tre[w][e0],     i0 = tim[w][e0];       // bitrev gather
    float r1 = tre[w][e0 + 1], i1 = tim[w][e0 + 1];
    wfft_dit_inv(r0, i0, r1, i1, lane);
    const size_t rb = ((size_t)((b << 4) | w) << 7);
    rout[rb + lane] = r0;
    rout[rb + lane + 64] = r1;
}

// ---------- gather ----------

__global__ void gather_kernel(const float4* __restrict__ sorted, const int* __restrict__ sortedIdx,
                              const float* __restrict__ rmesh, float* __restrict__ out, int n) {
    int t = blockIdx.x * blockDim.x + threadIdx.x;
    if (t >= n) return;
    float4 a = sorted[t];
    float wx[4], wy[4], wz[4];
    int ix[4], iy[4], iz[4];
    {
        float fl = floorf(a.x); int i0 = (int)fl; float x = a.x - fl - 0.5f; w4(x, wx);
        #pragma unroll
        for (int s = 0; s < 4; ++s) ix[s] = (i0 + s - 1) & 127;
    }
    {
        float fl = floorf(a.y); int i0 = (int)fl; float x = a.y - fl - 0.5f; w4(x, wy);
        #pragma unroll
        for (int s = 0; s < 4; ++s) iy[s] = (i0 + s - 1) & 127;
    }
    {
        float fl = floorf(a.z); int i0 = (int)fl; float x = a.z - fl - 0.5f; w4(x, wz);
        #pragma unroll
        for (int s = 0; s < 4; ++s) iz[s] = (i0 + s - 1) & 127;
    }
    float sum = 0.0f;
    #pragma unroll
    for (int i = 0; i < 4; ++i) {
        int bx = ix[i] << 14;
        float acc_i = 0.0f;
        #pragma unroll
        for (int j = 0; j < 4; ++j) {
            int bxy = bx | (iy[j] << 7);
            float acc_j = 0.0f;
            #pragma unroll
            for (int k = 0; k < 4; ++k) {
                acc_j += wz[k] * rmesh[bxy | iz[k]];
            }
            acc_i += wy[j] * acc_j;
        }
        sum += wx[i] * acc_i;
    }
    out[sortedIdx[t]] = sum - a.w * 0.79788456080286535588f;
}

// ---------- launch ----------

extern "C" void kernel_launch(void* const* d_in, const int* in_sizes, int n_in,
                              void* d_out, int out_size, void* d_ws, size_t ws_size,
                              hipStream_t stream) {
    const float* cell = (const float*)d_in[0];
    const float* pos  = (const float*)d_in[1];
    const float* q    = (const float*)d_in[2];
    float* out = (float*)d_out;
    const int n = in_sizes[2];

    char* ws = (char*)d_ws;
    size_t o = 0;
    float4* sorted   = (float4*)(ws + o); o += (size_t)n * 16;
    int* sortedIdx   = (int*)(ws + o);    o += (size_t)n * 4;  o = (o + 255) & ~(size_t)255;
    int* hist        = (int*)(ws + o);    o += (size_t)BINS * 4;            // also reorder cursor
    int* offsets     = (int*)(ws + o);    o += (size_t)(BINS + 4) * 4;
    int* partials    = (int*)(ws + o);    o += (size_t)SCAN_BLOCKS * 4; o = (o + 255) & ~(size_t)255;
    float2* mesh     = (float2*)(ws + o); o += (size_t)128 * 128 * ZP * 8;  // 9.4 MB
    float* rmesh     = (float*)(ws + o);  // NTOT * 4 = 8 MB

    zero_int_kernel<<<BINS / 256, 256, 0, stream>>>(hist, BINS);
    hist_kernel<<<(n + 255) / 256, 256, 0, stream>>>(cell, pos, hist, n);
    scan_local<<<SCAN_BLOCKS, 256, 0, stream>>>((const int4*)hist, (int4*)offsets, partials);
    scan_add<<<SCAN_BLOCKS, 256, 0, stream>>>((int4*)hist, (int4*)offsets, partials, offsets);
    reorder_kernel<<<(n + 255) / 256, 256, 0, stream>>>(cell, pos, q, hist, sorted, sortedIdx, n);

    cell_rho_kernel<<<4096, 512, 0, stream>>>(sorted, offsets, rmesh);

    fftZfwd<<<1024, 1024, 0, stream>>>(rmesh, mesh);
    fftYfwd<<<9 * 128, 512, 0, stream>>>(mesh);
    fftXGw<<<9 * 128, 512, 0, stream>>>(mesh, cell);
    fftYinv<<<9 * 128, 512, 0, stream>>>(mesh);
    fftZinv<<<1024, 1024, 0, stream>>>(mesh, rmesh);

    gather_kernel<<<(n + 255) / 256, 256, 0, stream>>>(sorted, sortedIdx, rmesh, out, n);
}

// Round 8
// 178.626 us; speedup vs baseline: 1.1098x; 1.1098x over previous
//
#include <hip/hip_runtime.h>
#include <math.h>

#define NTOT (128*128*128)
#define NBIN2 64                 // bins per axis (2 cells per bin)
#define BINS (NBIN2*NBIN2*NBIN2) // 262144
#define SCAN_BLOCKS 256

// scatter tiles: 16 x 16 x 8 cells
#define TSX 16
#define TSY 16
#define TSZ 8
#define NTILES 1024
#define NSB 600                  // scanned bins per tile: 10*10*6
#define MAPCAP 3072

#define ZP 72                    // complex-mesh z pitch (>= 65, mult of 8)

#define PI_F      3.14159265358979323846f
#define TWO_PI_F  6.28318530717958647692f
#define FOUR_PI_F 12.5663706143591729539f

// ---------- helpers ----------

__device__ inline void inv3x3(const float* __restrict__ c, float* inv, float* detOut) {
    float a = c[0], b = c[1], cc = c[2];
    float d = c[3], e = c[4], f  = c[5];
    float g = c[6], h = c[7], i  = c[8];
    float A = e * i - f * h;
    float B = f * g - d * i;
    float C = d * h - e * g;
    float det = a * A + b * B + cc * C;
    float r = 1.0f / det;
    inv[0] = A * r;              inv[1] = (cc * h - b * i) * r;  inv[2] = (b * f - cc * e) * r;
    inv[3] = B * r;              inv[4] = (a * i - cc * g) * r;  inv[5] = (cc * d - a * f) * r;
    inv[6] = C * r;              inv[7] = (b * g - a * h) * r;   inv[8] = (a * e - b * d) * r;
    *detOut = det;
}

__device__ inline void w4(float x, float* w) {
    float x2 = x * x, x3 = x2 * x;
    w[0] = (1.0f  - 6.0f  * x + 12.0f * x2 - 8.0f  * x3) * (1.0f / 48.0f);
    w[1] = (23.0f - 30.0f * x - 12.0f * x2 + 24.0f * x3) * (1.0f / 48.0f);
    w[2] = (23.0f + 30.0f * x - 12.0f * x2 - 24.0f * x3) * (1.0f / 48.0f);
    w[3] = (1.0f  + 6.0f  * x + 12.0f * x2 + 8.0f  * x3) * (1.0f / 48.0f);
}

__device__ inline void atom_rel(const float* __restrict__ cell,
                                const float* __restrict__ pos, int t,
                                float* rx, float* ry, float* rz) {
    float inv[9]; float det;
    inv3x3(cell, inv, &det);
    float px = pos[3 * t], py = pos[3 * t + 1], pz = pos[3 * t + 2];
    *rx = (px * inv[0] + py * inv[3] + pz * inv[6]) * 128.0f;
    *ry = (px * inv[1] + py * inv[4] + pz * inv[7]) * 128.0f;
    *rz = (px * inv[2] + py * inv[5] + pz * inv[8]) * 128.0f;
}

__device__ inline int bin_of(float rx, float ry, float rz) {
    int ix = ((int)floorf(rx)) & 127;
    int iy = ((int)floorf(ry)) & 127;
    int iz = ((int)floorf(rz)) & 127;
    return ((((ix >> 1) << 6) | (iy >> 1)) << 6) | (iz >> 1);
}

// rotate-by-r (r in 0..3) with static indices only (no scratch spill)
__device__ inline void rot4(const float* w, const int* a, int r, float* wr, int* ar) {
    #pragma unroll
    for (int k = 0; k < 4; ++k) {
        float v0 = w[k], v1 = w[(k + 1) & 3], v2 = w[(k + 2) & 3], v3 = w[(k + 3) & 3];
        int   b0 = a[k], b1 = a[(k + 1) & 3], b2 = a[(k + 2) & 3], b3 = a[(k + 3) & 3];
        float v = (r == 1) ? v1 : v0; v = (r == 2) ? v2 : v; v = (r == 3) ? v3 : v;
        int   b = (r == 1) ? b1 : b0; b = (r == 2) ? b2 : b; b = (r == 3) ? b3 : b;
        wr[k] = v; ar[k] = b;
    }
}

// ---------- binning ----------

__global__ void zero_int_kernel(int* __restrict__ p, int n) {
    int i = blockIdx.x * blockDim.x + threadIdx.x;
    if (i < n) p[i] = 0;
}

__global__ void hist_kernel(const float* __restrict__ cell, const float* __restrict__ pos,
                            int* __restrict__ hist, int n) {
    int t = blockIdx.x * blockDim.x + threadIdx.x;
    if (t >= n) return;
    float rx, ry, rz;
    atom_rel(cell, pos, t, &rx, &ry, &rz);
    atomicAdd(&hist[bin_of(rx, ry, rz)], 1);
}

__global__ __launch_bounds__(256) void scan_local(const int4* __restrict__ hist4,
                                                  int4* __restrict__ off4,
                                                  int* __restrict__ partials) {
    const int b = blockIdx.x, t = threadIdx.x;
    const int idx = b * 256 + t;
    int4 h = hist4[idx];
    int s = h.x + h.y + h.z + h.w;
    int lane = t & 63, wv = t >> 6;
    int v = s;
    #pragma unroll
    for (int d = 1; d < 64; d <<= 1) {
        int o = __shfl_up(v, d, 64);
        if (lane >= d) v += o;
    }
    __shared__ int wsum[4];
    if (lane == 63) wsum[wv] = v;
    __syncthreads();
    int add = 0;
    #pragma unroll
    for (int k = 0; k < 4; ++k) if (k < wv) add += wsum[k];
    int run = add + v - s;
    int4 o4;
    o4.x = run; run += h.x;
    o4.y = run; run += h.y;
    o4.z = run; run += h.z;
    o4.w = run; run += h.w;
    off4[idx] = o4;
    if (t == 255) partials[b] = run;
}

__global__ __launch_bounds__(256) void scan_add(int4* __restrict__ hist4,
                                                int4* __restrict__ off4,
                                                const int* __restrict__ partials,
                                                int* __restrict__ offsets) {
    const int b = blockIdx.x, t = threadIdx.x;
    int lane = t & 63, wv = t >> 6;
    int v = (t < b) ? partials[t] : 0;
    #pragma unroll
    for (int d = 32; d >= 1; d >>= 1) v += __shfl_xor(v, d, 64);
    __shared__ int ws2[4];
    __shared__ int base_s;
    if (lane == 0) ws2[wv] = v;
    __syncthreads();
    if (t == 0) base_s = ws2[0] + ws2[1] + ws2[2] + ws2[3];
    __syncthreads();
    const int base = base_s;
    const int idx = b * 256 + t;
    int4 o4 = off4[idx];
    o4.x += base; o4.y += base; o4.z += base; o4.w += base;
    off4[idx]  = o4;
    hist4[idx] = o4;
    if (b == SCAN_BLOCKS - 1 && t == 255) offsets[BINS] = base + partials[b];
}

__global__ void reorder_kernel(const float* __restrict__ cell, const float* __restrict__ pos,
                               const float* __restrict__ q, int* __restrict__ cursor,
                               float4* __restrict__ sorted, int* __restrict__ sortedIdx, int n) {
    int t = blockIdx.x * blockDim.x + threadIdx.x;
    if (t >= n) return;
    float rx, ry, rz;
    atom_rel(cell, pos, t, &rx, &ry, &rz);
    int p = atomicAdd(&cursor[bin_of(rx, ry, rz)], 1);
    sorted[p] = make_float4(rx, ry, rz, q[t]);
    sortedIdx[p] = t;
}

// ---------- LDS-tiled scatter, flat work list, lane-staggered atomics ----------

__global__ __launch_bounds__(512) void tile_scatter_kernel(const float4* __restrict__ atoms,
                                                           const int* __restrict__ offsets,
                                                           float* __restrict__ rmesh) {
    const int tile = blockIdx.x;             // 1024 tiles of 16x16x8 cells
    const int tz = tile & 15, ty = (tile >> 4) & 7, tx = tile >> 7;
    const int ox = tx << 4, oy = ty << 4, oz = tz << 3;

    __shared__ float acc[TSX * TSY * TSZ];   // [lx<<7 | ly<<3 | lz]
    __shared__ int P[NSB + 1];
    __shared__ int bstart[NSB];
    __shared__ int wsum[8];
    __shared__ unsigned short map[MAPCAP];

    const int t = threadIdx.x;
    for (int c = t; c < TSX * TSY * TSZ; c += 512) acc[c] = 0.0f;

    // bins: thread t < 300 owns s = 2t, 2t+1 of the 10x10x6 scan region
    int c0 = 0, c1 = 0;
    if (t < 300) {
        #pragma unroll
        for (int k = 0; k < 2; ++k) {
            int s  = 2 * t + k;
            int dx = s / 60, r = s - dx * 60;
            int dy = r / 6,  dz = r - dy * 6;
            int bx = (8 * tx - 1 + dx) & (NBIN2 - 1);
            int by = (8 * ty - 1 + dy) & (NBIN2 - 1);
            int bz = (4 * tz - 1 + dz) & (NBIN2 - 1);
            int bin = (((bx << 6) | by) << 6) | bz;
            int st  = offsets[bin];
            int cnt = offsets[bin + 1] - st;
            bstart[s] = st;
            if (k == 0) c0 = cnt; else c1 = cnt;
        }
    }
    int s = c0 + c1;
    int lane = t & 63, wv = t >> 6;
    int v = s;
    #pragma unroll
    for (int d = 1; d < 64; d <<= 1) {
        int o = __shfl_up(v, d, 64);
        if (lane >= d) v += o;
    }
    if (lane == 63) wsum[wv] = v;
    __syncthreads();
    int add = 0;
    for (int k = 0; k < wv; ++k) add += wsum[k];
    int run = add + v - s;
    if (t < 300) { P[2 * t] = run; P[2 * t + 1] = run + c0; }
    if (t == 299) P[NSB] = run + c0 + c1;
    __syncthreads();
    if (t < 300) {
        #pragma unroll
        for (int k = 0; k < 2; ++k) {
            int sb = 2 * t + k;
            int lo = P[sb], hi = P[sb + 1];
            if (hi > MAPCAP) hi = MAPCAP;
            for (int m = lo; m < hi; ++m) map[m] = (unsigned short)sb;
        }
    }
    __syncthreads();

    // lane-dependent loop phases: spread concurrent atomics across LDS banks
    const int rk = lane & 3;              // z-phase
    const int rj = (lane >> 2) & 3;       // y-phase

    const int total = P[NSB];
    for (int i = t; i < total; i += 512) {
        int j;
        if (i < MAPCAP) {
            j = map[i];
        } else {                              // statistically never
            int lo = 0, hi = NSB - 1;
            while (lo < hi) { int mid = (lo + hi + 1) >> 1; if (P[mid] <= i) lo = mid; else hi = mid - 1; }
            j = lo;
        }
        float4 a = atoms[bstart[j] + (i - P[j])];

        float wx[4], wy[4], wz[4];
        int ax[4], ay[4], az[4];
        int vx = 0, vy = 0, vz = 0;
        {
            float fl = floorf(a.x); int i0 = (int)fl; float xx = a.x - fl - 0.5f; w4(xx, wx);
            #pragma unroll
            for (int s2 = 0; s2 < 4; ++s2) {
                int cc = (i0 + s2 - 1) & 127; int l = (cc - ox) & 127;
                int ok = (l < TSX); vx |= ok;
                ax[s2] = (l & (TSX - 1)) << 7;
                if (!ok) wx[s2] = 0.0f;
            }
        }
        {
            float fl = floorf(a.y); int i0 = (int)fl; float yy = a.y - fl - 0.5f; w4(yy, wy);
            #pragma unroll
            for (int s2 = 0; s2 < 4; ++s2) {
                int cc = (i0 + s2 - 1) & 127; int l = (cc - oy) & 127;
                int ok = (l < TSY); vy |= ok;
                ay[s2] = (l & (TSY - 1)) << 3;
                if (!ok) wy[s2] = 0.0f;
            }
        }
        {
            float fl = floorf(a.z); int i0 = (int)fl; float zz = a.z - fl - 0.5f; w4(zz, wz);
            #pragma unroll
            for (int s2 = 0; s2 < 4; ++s2) {
                int cc = (i0 + s2 - 1) & 127; int l = (cc - oz) & 127;
                int ok = (l < TSZ); vz |= ok;
                az[s2] = l & (TSZ - 1);
                if (!ok) wz[s2] = 0.0f;
            }
        }
        if (!(vx & vy & vz)) continue;

        // rotate y/z stencils by lane phase (static-index selects)
        float wyr[4], wzr[4]; int ayr[4], azr[4];
        rot4(wy, ay, rj, wyr, ayr);
        rot4(wz, az, rk, wzr, azr);

        float qc = a.w;
        #pragma unroll
        for (int i2 = 0; i2 < 4; ++i2) {
            float qx = qc * wx[i2];
            #pragma unroll
            for (int j2 = 0; j2 < 4; ++j2) {
                float qxy = qx * wyr[j2];
                int bxy = ax[i2] | ayr[j2];
                #pragma unroll
                for (int k2 = 0; k2 < 4; ++k2) {
                    float val = qxy * wzr[k2];
                    if (val != 0.0f) atomicAdd(&acc[bxy | azr[k2]], val);
                }
            }
        }
    }
    __syncthreads();

    for (int c = t; c < TSX * TSY * TSZ; c += 512) {
        int lx = c >> 7, ly = (c >> 3) & 15, lz = c & 7;
        int g = ((ox + lx) << 14) | ((oy + ly) << 7) | (oz + lz);
        rmesh[g] = acc[c];
    }
}

// ---------- register-shuffle 128-pt FFT (wave per line) ----------

__device__ inline void bfly_dif(float& rr, float& ii, int h, bool hi, float cs, float sn) {
    float pr = __shfl_xor(rr, h), pi = __shfl_xor(ii, h);
    float br = hi ? (pr - rr) : (rr + pr);
    float bi = hi ? (pi - ii) : (ii + pi);
    rr = cs * br - sn * bi;
    ii = cs * bi + sn * br;
}

__device__ inline void bfly_dit(float& rr, float& ii, int h, bool hi, float cs, float sn) {
    float pr = __shfl_xor(rr, h), pi = __shfl_xor(ii, h);
    float xr = hi ? rr : pr, xi = hi ? ii : pi;
    float br = hi ? pr : rr, bi = hi ? pi : ii;
    float tr = cs * xr - sn * xi, ti = cs * xi + sn * xr;
    rr = hi ? (br - tr) : (br + tr);
    ii = hi ? (bi - ti) : (bi + ti);
}

__device__ inline void wfft_dif_fwd(float& r0, float& i0, float& r1, float& i1, int lane) {
    {
        float ang = -PI_F * (float)lane * (1.0f / 64.0f);
        float sn, cs; __sincosf(ang, &sn, &cs);
        float ar = r0 + r1, ai = i0 + i1;
        float dr = r0 - r1, di = i0 - i1;
        r0 = ar; i0 = ai;
        r1 = cs * dr - sn * di;
        i1 = cs * di + sn * dr;
    }
    #pragma unroll
    for (int h = 32; h >= 1; h >>= 1) {
        int pos = lane & (h - 1);
        bool hi = (lane & h) != 0;
        float ang = hi ? (-PI_F * (float)pos / (float)h) : 0.0f;
        float sn, cs; __sincosf(ang, &sn, &cs);
        bfly_dif(r0, i0, h, hi, cs, sn);
        bfly_dif(r1, i1, h, hi, cs, sn);
    }
}

__device__ inline void wfft_dit_inv(float& r0, float& i0, float& r1, float& i1, int lane) {
    #pragma unroll
    for (int h = 1; h <= 32; h <<= 1) {
        int pos = lane & (h - 1);
        bool hi = (lane & h) != 0;
        float ang = PI_F * (float)pos / (float)h;
        float sn, cs; __sincosf(ang, &sn, &cs);
        bfly_dit(r0, i0, h, hi, cs, sn);
        bfly_dit(r1, i1, h, hi, cs, sn);
    }
    {
        float ang = PI_F * (float)lane * (1.0f / 64.0f);
        float sn, cs; __sincosf(ang, &sn, &cs);
        float tr = cs * r1 - sn * i1, ti = cs * i1 + sn * r1;
        float nr = r0 + tr, ni = i0 + ti;
        r1 = r0 - tr; i1 = i0 - ti;
        r0 = nr; i0 = ni;
    }
}

// ---------- z forward: real -> complex natural order (Hermitian prefix) ----------

__global__ __launch_bounds__(1024) void fftZfwd(const float* __restrict__ rin,
                                                float2* __restrict__ mesh) {
    __shared__ float tre[16][132], tim[16][132];
    const int t = threadIdx.x, b = blockIdx.x;
    for (int u = t; u < 2048; u += 1024) {
        int l = u >> 7, e = u & 127;
        tre[l][e] = rin[((size_t)((b << 4) | l) << 7) + e];
    }
    __syncthreads();
    const int w = t >> 6, lane = t & 63;
    float r0 = tre[w][lane],      i0 = 0.0f;
    float r1 = tre[w][lane + 64], i1 = 0.0f;
    wfft_dif_fwd(r0, i0, r1, i1, lane);
    int e0 = (int)(__brev((unsigned)lane) >> 25);
    tre[w][e0] = r0;     tim[w][e0] = i0;
    tre[w][e0 + 1] = r1; tim[w][e0 + 1] = i1;
    __syncthreads();
    for (int u = t; u < 2048; u += 1024) {
        int l = u >> 7, e = u & 127;
        if (e < ZP)
            mesh[(size_t)((b << 4) | l) * ZP + e] = make_float2(tre[l][e], tim[l][e]);
    }
}

// ---------- y forward: natural in -> bit-reversed positions ----------

__global__ __launch_bounds__(512) void fftYfwd(float2* __restrict__ mesh) {
    __shared__ float tre[8][132], tim[8][132];
    const int t = threadIdx.x, b = blockIdx.x;
    const int x = b & 127, zf0 = (b >> 7) << 3;
    const size_t rb = ((size_t)(x << 7)) * ZP + zf0;
    for (int u = t; u < 1024; u += 512) {
        int e = u >> 3, dz = u & 7;
        float2 vv = mesh[rb + (size_t)e * ZP + dz];
        tre[dz][e] = vv.x; tim[dz][e] = vv.y;
    }
    __syncthreads();
    const int w = t >> 6, lane = t & 63;
    float r0 = tre[w][lane],      i0 = tim[w][lane];
    float r1 = tre[w][lane + 64], i1 = tim[w][lane + 64];
    wfft_dif_fwd(r0, i0, r1, i1, lane);
    tre[w][lane] = r0;      tim[w][lane] = i0;
    tre[w][lane + 64] = r1; tim[w][lane + 64] = i1;
    __syncthreads();
    for (int u = t; u < 1024; u += 512) {
        int e = u >> 3, dz = u & 7;
        mesh[rb + (size_t)e * ZP + dz] = make_float2(tre[dz][e], tim[dz][e]);
    }
}

// ---------- fused x: DIF fwd -> G(k) at rev-indexed k -> DIT inv ----------

__global__ __launch_bounds__(512) void fftXGw(float2* __restrict__ mesh,
                                              const float* __restrict__ cell) {
    __shared__ float tre[8][132], tim[8][132];
    const int t = threadIdx.x, b = blockIdx.x;
    const int py = b & 127, zf0 = (b >> 7) << 3;
    for (int u = t; u < 1024; u += 512) {
        int e = u >> 3, dz = u & 7;
        float2 vv = mesh[(size_t)((e << 7) | py) * ZP + zf0 + dz];
        tre[dz][e] = vv.x; tim[dz][e] = vv.y;
    }
    __syncthreads();
    const int w = t >> 6, lane = t & 63;
    float r0 = tre[w][lane],      i0 = tim[w][lane];
    float r1 = tre[w][lane + 64], i1 = tim[w][lane + 64];
    wfft_dif_fwd(r0, i0, r1, i1, lane);
    {
        float inv[9]; float det; inv3x3(cell, inv, &det);
        float invVol = 1.0f / fabsf(det);
        int my = (int)(__brev((unsigned)py) >> 25);
        int mz = zf0 + w;
        float fy = (my < 64) ? (float)my : (float)(my - 128);
        float fz = (mz < 64) ? (float)mz : (float)(mz - 128);
        int mx0 = (int)(__brev((unsigned)lane) >> 25);
        #pragma unroll
        for (int s = 0; s < 2; ++s) {
            int mx = mx0 + s;
            float fx = (mx < 64) ? (float)mx : (float)(mx - 128);
            float kx = TWO_PI_F * (fx * inv[0] + fy * inv[1] + fz * inv[2]);
            float ky = TWO_PI_F * (fx * inv[3] + fy * inv[4] + fz * inv[5]);
            float kz = TWO_PI_F * (fx * inv[6] + fy * inv[7] + fz * inv[8]);
            float ksq = kx * kx + ky * ky + kz * kz;
            float G = (ksq == 0.0f) ? 0.0f
                      : FOUR_PI_F / ksq * __expf(-0.5f * ksq) * invVol;
            if (s == 0) { r0 *= G; i0 *= G; } else { r1 *= G; i1 *= G; }
        }
    }
    wfft_dit_inv(r0, i0, r1, i1, lane);
    tre[w][lane] = r0;      tim[w][lane] = i0;
    tre[w][lane + 64] = r1; tim[w][lane + 64] = i1;
    __syncthreads();
    for (int u = t; u < 1024; u += 512) {
        int e = u >> 3, dz = u & 7;
        mesh[(size_t)((e << 7) | py) * ZP + zf0 + dz] =
            make_float2(tre[dz][e], tim[dz][e]);
    }
}

// ---------- y inverse: bit-reversed positions in -> natural out ----------

__global__ __launch_bounds__(512) void fftYinv(float2* __restrict__ mesh) {
    __shared__ float tre[8][132], tim[8][132];
    const int t = threadIdx.x, b = blockIdx.x;
    const int x = b & 127, zf0 = (b >> 7) << 3;
    const size_t rb = ((size_t)(x << 7)) * ZP + zf0;
    for (int u = t; u < 1024; u += 512) {
        int e = u >> 3, dz = u & 7;
        float2 vv = mesh[rb + (size_t)e * ZP + dz];
        tre[dz][e] = vv.x; tim[dz][e] = vv.y;
    }
    __syncthreads();
    const int w = t >> 6, lane = t & 63;
    float r0 = tre[w][lane],      i0 = tim[w][lane];
    float r1 = tre[w][lane + 64], i1 = tim[w][lane + 64];
    wfft_dit_inv(r0, i0, r1, i1, lane);
    tre[w][lane] = r0;      tim[w][lane] = i0;
    tre[w][lane + 64] = r1; tim[w][lane + 64] = i1;
    __syncthreads();
    for (int u = t; u < 1024; u += 512) {
        int e = u >> 3, dz = u & 7;
        mesh[rb + (size_t)e * ZP + dz] = make_float2(tre[dz][e], tim[dz][e]);
    }
}

// ---------- z inverse: Hermitian mirror -> real out ----------

__global__ __launch_bounds__(1024) void fftZinv(const float2* __restrict__ mesh,
                                                float* __restrict__ rout) {
    __shared__ float tre[16][132], tim[16][132];
    const int t = threadIdx.x, b = blockIdx.x;
    for (int u = t; u < 2048; u += 1024) {
        int l = u >> 7, e = u & 127;
        int src = (e <= 64) ? e : 128 - e;
        float2 vv = mesh[(size_t)((b << 4) | l) * ZP + src];
        tre[l][e] = vv.x;
        tim[l][e] = (e <= 64) ? vv.y : -vv.y;
    }
    __syncthreads();
    const int w = t >> 6, lane = t & 63;
    int e0 = (int)(__brev((unsigned)lane) >> 25);
    float r0 = tre[w][e0],     i0 = tim[w][e0];
    float r1 = tre[w][e0 + 1], i1 = tim[w][e0 + 1];
    wfft_dit_inv(r0, i0, r1, i1, lane);
    const size_t rb = ((size_t)((b << 4) | w) << 7);
    rout[rb + lane] = r0;
    rout[rb + lane + 64] = r1;
}

// ---------- gather ----------

__global__ void gather_kernel(const float4* __restrict__ sorted, const int* __restrict__ sortedIdx,
                              const float* __restrict__ rmesh, float* __restrict__ out, int n) {
    int t = blockIdx.x * blockDim.x + threadIdx.x;
    if (t >= n) return;
    float4 a = sorted[t];
    float wx[4], wy[4], wz[4];
    int ix[4], iy[4], iz[4];
    {
        float fl = floorf(a.x); int i0 = (int)fl; float x = a.x - fl - 0.5f; w4(x, wx);
        #pragma unroll
        for (int s = 0; s < 4; ++s) ix[s] = (i0 + s - 1) & 127;
    }
    {
        float fl = floorf(a.y); int i0 = (int)fl; float x = a.y - fl - 0.5f; w4(x, wy);
        #pragma unroll
        for (int s = 0; s < 4; ++s) iy[s] = (i0 + s - 1) & 127;
    }
    {
        float fl = floorf(a.z); int i0 = (int)fl; float x = a.z - fl - 0.5f; w4(x, wz);
        #pragma unroll
        for (int s = 0; s < 4; ++s) iz[s] = (i0 + s - 1) & 127;
    }
    float sum = 0.0f;
    #pragma unroll
    for (int i = 0; i < 4; ++i) {
        int bx = ix[i] << 14;
        float acc_i = 0.0f;
        #pragma unroll
        for (int j = 0; j < 4; ++j) {
            int bxy = bx | (iy[j] << 7);
            float acc_j = 0.0f;
            #pragma unroll
            for (int k = 0; k < 4; ++k) {
                acc_j += wz[k] * rmesh[bxy | iz[k]];
            }
            acc_i += wy[j] * acc_j;
        }
        sum += wx[i] * acc_i;
    }
    out[sortedIdx[t]] = sum - a.w * 0.79788456080286535588f;
}

// ---------- launch ----------

extern "C" void kernel_launch(void* const* d_in, const int* in_sizes, int n_in,
                              void* d_out, int out_size, void* d_ws, size_t ws_size,
                              hipStream_t stream) {
    const float* cell = (const float*)d_in[0];
    const float* pos  = (const float*)d_in[1];
    const float* q    = (const float*)d_in[2];
    float* out = (float*)d_out;
    const int n = in_sizes[2];

    char* ws = (char*)d_ws;
    size_t o = 0;
    float4* sorted   = (float4*)(ws + o); o += (size_t)n * 16;
    int* sortedIdx   = (int*)(ws + o);    o += (size_t)n * 4;  o = (o + 255) & ~(size_t)255;
    int* hist        = (int*)(ws + o);    o += (size_t)BINS * 4;            // also reorder cursor
    int* offsets     = (int*)(ws + o);    o += (size_t)(BINS + 4) * 4;
    int* partials    = (int*)(ws + o);    o += (size_t)SCAN_BLOCKS * 4; o = (o + 255) & ~(size_t)255;
    float2* mesh     = (float2*)(ws + o); o += (size_t)128 * 128 * ZP * 8;  // 9.4 MB
    float* rmesh     = (float*)(ws + o);  // NTOT * 4 = 8 MB

    zero_int_kernel<<<BINS / 256, 256, 0, stream>>>(hist, BINS);
    hist_kernel<<<(n + 255) / 256, 256, 0, stream>>>(cell, pos, hist, n);
    scan_local<<<SCAN_BLOCKS, 256, 0, stream>>>((const int4*)hist, (int4*)offsets, partials);
    scan_add<<<SCAN_BLOCKS, 256, 0, stream>>>((int4*)hist, (int4*)offsets, partials, offsets);
    reorder_kernel<<<(n + 255) / 256, 256, 0, stream>>>(cell, pos, q, hist, sorted, sortedIdx, n);

    tile_scatter_kernel<<<NTILES, 512, 0, stream>>>(sorted, offsets, rmesh);

    fftZfwd<<<1024, 1024, 0, stream>>>(rmesh, mesh);
    fftYfwd<<<9 * 128, 512, 0, stream>>>(mesh);
    fftXGw<<<9 * 128, 512, 0, stream>>>(mesh, cell);
    fftYinv<<<9 * 128, 512, 0, stream>>>(mesh);
    fftZinv<<<1024, 1024, 0, stream>>>(mesh, rmesh);

    gather_kernel<<<(n + 255) / 256, 256, 0, stream>>>(sorted, sortedIdx, rmesh, out, n);
}

// Round 9
// 164.049 us; speedup vs baseline: 1.2085x; 1.0889x over previous
//
#include <hip/hip_runtime.h>
#include <math.h>

#define NTOT (128*128*128)
#define NBIN2 64                 // bins per axis (2 cells per bin)
#define BINS (NBIN2*NBIN2*NBIN2) // 262144
#define SCAN_BLOCKS 256

#define ZP 72                    // complex-mesh z pitch (>= 65, mult of 8)

#define PI_F      3.14159265358979323846f
#define TWO_PI_F  6.28318530717958647692f
#define FOUR_PI_F 12.5663706143591729539f

// ---------- helpers ----------

__device__ inline void inv3x3(const float* __restrict__ c, float* inv, float* detOut) {
    float a = c[0], b = c[1], cc = c[2];
    float d = c[3], e = c[4], f  = c[5];
    float g = c[6], h = c[7], i  = c[8];
    float A = e * i - f * h;
    float B = f * g - d * i;
    float C = d * h - e * g;
    float det = a * A + b * B + cc * C;
    float r = 1.0f / det;
    inv[0] = A * r;              inv[1] = (cc * h - b * i) * r;  inv[2] = (b * f - cc * e) * r;
    inv[3] = B * r;              inv[4] = (a * i - cc * g) * r;  inv[5] = (cc * d - a * f) * r;
    inv[6] = C * r;              inv[7] = (b * g - a * h) * r;   inv[8] = (a * e - b * d) * r;
    *detOut = det;
}

__device__ inline void w4(float x, float* w) {
    float x2 = x * x, x3 = x2 * x;
    w[0] = (1.0f  - 6.0f  * x + 12.0f * x2 - 8.0f  * x3) * (1.0f / 48.0f);
    w[1] = (23.0f - 30.0f * x - 12.0f * x2 + 24.0f * x3) * (1.0f / 48.0f);
    w[2] = (23.0f + 30.0f * x - 12.0f * x2 - 24.0f * x3) * (1.0f / 48.0f);
    w[3] = (1.0f  + 6.0f  * x + 12.0f * x2 + 8.0f  * x3) * (1.0f / 48.0f);
}

__device__ inline void atom_rel(const float* __restrict__ cell,
                                const float* __restrict__ pos, int t,
                                float* rx, float* ry, float* rz) {
    float inv[9]; float det;
    inv3x3(cell, inv, &det);
    float px = pos[3 * t], py = pos[3 * t + 1], pz = pos[3 * t + 2];
    *rx = (px * inv[0] + py * inv[3] + pz * inv[6]) * 128.0f;
    *ry = (px * inv[1] + py * inv[4] + pz * inv[7]) * 128.0f;
    *rz = (px * inv[2] + py * inv[5] + pz * inv[8]) * 128.0f;
}

__device__ inline int bin_of(float rx, float ry, float rz) {
    int ix = ((int)floorf(rx)) & 127;
    int iy = ((int)floorf(ry)) & 127;
    int iz = ((int)floorf(rz)) & 127;
    return ((((ix >> 1) << 6) | (iy >> 1)) << 6) | (iz >> 1);
}

// periodic wrap of a cell-units offset into (-64, 64]
__device__ inline float wrap128(float u) {
    u = (u > 64.0f) ? u - 128.0f : u;
    u = (u < -64.0f) ? u + 128.0f : u;
    return u;
}

// cubic B-spline M4 assignment weight (unnormalized: true weight = this / 6)
__device__ inline float bspline(float u) {
    float a = fabsf(u);
    float t = fmaxf(2.0f - a, 0.0f);
    float s = fmaxf(1.0f - a, 0.0f);
    return t * t * t - 4.0f * s * s * s;
}

// ---------- binning ----------

__global__ void zero_int_kernel(int* __restrict__ p, int n) {
    int i = blockIdx.x * blockDim.x + threadIdx.x;
    if (i < n) p[i] = 0;
}

__global__ void hist_kernel(const float* __restrict__ cell, const float* __restrict__ pos,
                            int* __restrict__ hist, int n) {
    int t = blockIdx.x * blockDim.x + threadIdx.x;
    if (t >= n) return;
    float rx, ry, rz;
    atom_rel(cell, pos, t, &rx, &ry, &rz);
    atomicAdd(&hist[bin_of(rx, ry, rz)], 1);
}

__global__ __launch_bounds__(256) void scan_local(const int4* __restrict__ hist4,
                                                  int4* __restrict__ off4,
                                                  int* __restrict__ partials) {
    const int b = blockIdx.x, t = threadIdx.x;
    const int idx = b * 256 + t;
    int4 h = hist4[idx];
    int s = h.x + h.y + h.z + h.w;
    int lane = t & 63, wv = t >> 6;
    int v = s;
    #pragma unroll
    for (int d = 1; d < 64; d <<= 1) {
        int o = __shfl_up(v, d, 64);
        if (lane >= d) v += o;
    }
    __shared__ int wsum[4];
    if (lane == 63) wsum[wv] = v;
    __syncthreads();
    int add = 0;
    #pragma unroll
    for (int k = 0; k < 4; ++k) if (k < wv) add += wsum[k];
    int run = add + v - s;
    int4 o4;
    o4.x = run; run += h.x;
    o4.y = run; run += h.y;
    o4.z = run; run += h.z;
    o4.w = run; run += h.w;
    off4[idx] = o4;
    if (t == 255) partials[b] = run;
}

__global__ __launch_bounds__(256) void scan_add(int4* __restrict__ hist4,
                                                int4* __restrict__ off4,
                                                const int* __restrict__ partials,
                                                int* __restrict__ offsets) {
    const int b = blockIdx.x, t = threadIdx.x;
    int lane = t & 63, wv = t >> 6;
    int v = (t < b) ? partials[t] : 0;
    #pragma unroll
    for (int d = 32; d >= 1; d >>= 1) v += __shfl_xor(v, d, 64);
    __shared__ int ws2[4];
    __shared__ int base_s;
    if (lane == 0) ws2[wv] = v;
    __syncthreads();
    if (t == 0) base_s = ws2[0] + ws2[1] + ws2[2] + ws2[3];
    __syncthreads();
    const int base = base_s;
    const int idx = b * 256 + t;
    int4 o4 = off4[idx];
    o4.x += base; o4.y += base; o4.z += base; o4.w += base;
    off4[idx]  = o4;
    hist4[idx] = o4;
    if (b == SCAN_BLOCKS - 1 && t == 255) offsets[BINS] = base + partials[b];
}

__global__ void reorder_kernel(const float* __restrict__ cell, const float* __restrict__ pos,
                               const float* __restrict__ q, int* __restrict__ cursor,
                               float4* __restrict__ sorted, int* __restrict__ sortedIdx, int n) {
    int t = blockIdx.x * blockDim.x + threadIdx.x;
    if (t >= n) return;
    float rx, ry, rz;
    atom_rel(cell, pos, t, &rx, &ry, &rz);
    int p = atomicAdd(&cursor[bin_of(rx, ry, rz)], 1);
    sorted[p] = make_float4(rx, ry, rz, q[t]);
    sortedIdx[p] = t;
}

// ---------- column scatter: thread owns 4 z-cells, accumulates in registers ----------
// No atomics, no LDS. Atoms gathered via bin-CSR (z-contiguous global ranges).

__global__ __launch_bounds__(512) void column_scatter_kernel(const float4* __restrict__ atoms,
                                                             const int* __restrict__ offsets,
                                                             float* __restrict__ rmesh) {
    const int b = blockIdx.x;                      // 1024 = 16 x 16 xy-tiles x 4 z-quarters
    const int txt = b & 15, tyt = (b >> 4) & 15, zq = b >> 8;
    const int t = threadIdx.x;
    const int chunk_l = t & 7, cyl = (t >> 3) & 7, cxl = t >> 6;
    const int cx = (txt << 3) | cxl;
    const int cy = (tyt << 3) | cyl;
    const int cz0 = (((zq << 3) | chunk_l) << 2);  // 32 chunks of 4 cells

    float c0 = 0.0f, c1 = 0.0f, c2 = 0.0f, c3 = 0.0f;

    const float fcx = (float)cx, fcy = (float)cy, fcz = (float)cz0;

    // neighborhood bins: x cells [cx-2, cx+1] -> 2 or 3 bins; same for y
    const int xb0 = ((cx - 2) & 127) >> 1;
    const int yb0 = ((cy - 2) & 127) >> 1;
    const int nbx = 2 + (cx & 1);
    const int nby = 2 + (cy & 1);
    // z: atoms iz in [cz0-2, cz0+4] -> 4 consecutive bins (maybe wrapping)
    const int zb0 = ((cz0 - 2) & 127) >> 1;
    int len0 = 64 - zb0; if (len0 > 4) len0 = 4;
    const int len1 = 4 - len0;

    // flattened persistent iterator over (i2, j2, run) ranges
    int i2 = 0, j2 = 0, r = -1;
    int i = 0, e = 0;
    for (;;) {
        while (i >= e) {                 // advance to next non-empty range
            ++r;
            if (r >= 2 || (r == 1 && len1 == 0)) {
                r = 0;
                if (++j2 >= nby) { j2 = 0; ++i2; }
            }
            if (i2 >= nbx) { i = 0; e = -1; break; }   // done sentinel
            int bx = (xb0 + i2) & 63;
            int by = (yb0 + j2) & 63;
            int binBase = ((bx << 6) | by) << 6;
            if (r == 0) { i = offsets[binBase + zb0]; e = offsets[binBase + zb0 + len0]; }
            else        { i = offsets[binBase];       e = offsets[binBase + len1]; }
        }
        if (e < 0) break;                // lane finished

        float4 a = atoms[i]; ++i;

        float ux = wrap128(a.x - fcx);
        float wx = bspline(ux);
        float uy = wrap128(a.y - fcy);
        float wy = bspline(uy);
        float wxy = a.w * wx * wy * (1.0f / 216.0f);
        float uz = wrap128(a.z - fcz);
        c0 += wxy * bspline(uz);
        c1 += wxy * bspline(uz - 1.0f);
        c2 += wxy * bspline(uz - 2.0f);
        c3 += wxy * bspline(uz - 3.0f);
    }

    const size_t base = ((size_t)cx << 14) | ((size_t)cy << 7) | (size_t)cz0;
    *(float4*)&rmesh[base] = make_float4(c0, c1, c2, c3);
}

// ---------- register-shuffle 128-pt FFT (wave per line) ----------

__device__ inline void bfly_dif(float& rr, float& ii, int h, bool hi, float cs, float sn) {
    float pr = __shfl_xor(rr, h), pi = __shfl_xor(ii, h);
    float br = hi ? (pr - rr) : (rr + pr);
    float bi = hi ? (pi - ii) : (ii + pi);
    rr = cs * br - sn * bi;
    ii = cs * bi + sn * br;
}

__device__ inline void bfly_dit(float& rr, float& ii, int h, bool hi, float cs, float sn) {
    float pr = __shfl_xor(rr, h), pi = __shfl_xor(ii, h);
    float xr = hi ? rr : pr, xi = hi ? ii : pi;
    float br = hi ? pr : rr, bi = hi ? pi : ii;
    float tr = cs * xr - sn * xi, ti = cs * xi + sn * xr;
    rr = hi ? (br - tr) : (br + tr);
    ii = hi ? (bi - ti) : (bi + ti);
}

__device__ inline void wfft_dif_fwd(float& r0, float& i0, float& r1, float& i1, int lane) {
    {
        float ang = -PI_F * (float)lane * (1.0f / 64.0f);
        float sn, cs; __sincosf(ang, &sn, &cs);
        float ar = r0 + r1, ai = i0 + i1;
        float dr = r0 - r1, di = i0 - i1;
        r0 = ar; i0 = ai;
        r1 = cs * dr - sn * di;
        i1 = cs * di + sn * dr;
    }
    #pragma unroll
    for (int h = 32; h >= 1; h >>= 1) {
        int pos = lane & (h - 1);
        bool hi = (lane & h) != 0;
        float ang = hi ? (-PI_F * (float)pos / (float)h) : 0.0f;
        float sn, cs; __sincosf(ang, &sn, &cs);
        bfly_dif(r0, i0, h, hi, cs, sn);
        bfly_dif(r1, i1, h, hi, cs, sn);
    }
}

__device__ inline void wfft_dit_inv(float& r0, float& i0, float& r1, float& i1, int lane) {
    #pragma unroll
    for (int h = 1; h <= 32; h <<= 1) {
        int pos = lane & (h - 1);
        bool hi = (lane & h) != 0;
        float ang = PI_F * (float)pos / (float)h;
        float sn, cs; __sincosf(ang, &sn, &cs);
        bfly_dit(r0, i0, h, hi, cs, sn);
        bfly_dit(r1, i1, h, hi, cs, sn);
    }
    {
        float ang = PI_F * (float)lane * (1.0f / 64.0f);
        float sn, cs; __sincosf(ang, &sn, &cs);
        float tr = cs * r1 - sn * i1, ti = cs * i1 + sn * r1;
        float nr = r0 + tr, ni = i0 + ti;
        r1 = r0 - tr; i1 = i0 - ti;
        r0 = nr; i0 = ni;
    }
}

// ---------- z forward: real -> complex natural order (Hermitian prefix) ----------

__global__ __launch_bounds__(1024) void fftZfwd(const float* __restrict__ rin,
                                                float2* __restrict__ mesh) {
    __shared__ float tre[16][132], tim[16][132];
    const int t = threadIdx.x, b = blockIdx.x;
    for (int u = t; u < 2048; u += 1024) {
        int l = u >> 7, e = u & 127;
        tre[l][e] = rin[((size_t)((b << 4) | l) << 7) + e];
    }
    __syncthreads();
    const int w = t >> 6, lane = t & 63;
    float r0 = tre[w][lane],      i0 = 0.0f;
    float r1 = tre[w][lane + 64], i1 = 0.0f;
    wfft_dif_fwd(r0, i0, r1, i1, lane);
    int e0 = (int)(__brev((unsigned)lane) >> 25);
    tre[w][e0] = r0;     tim[w][e0] = i0;
    tre[w][e0 + 1] = r1; tim[w][e0 + 1] = i1;
    __syncthreads();
    for (int u = t; u < 2048; u += 1024) {
        int l = u >> 7, e = u & 127;
        if (e < ZP)
            mesh[(size_t)((b << 4) | l) * ZP + e] = make_float2(tre[l][e], tim[l][e]);
    }
}

// ---------- y forward: natural in -> bit-reversed positions ----------

__global__ __launch_bounds__(512) void fftYfwd(float2* __restrict__ mesh) {
    __shared__ float tre[8][132], tim[8][132];
    const int t = threadIdx.x, b = blockIdx.x;
    const int x = b & 127, zf0 = (b >> 7) << 3;
    const size_t rb = ((size_t)(x << 7)) * ZP + zf0;
    for (int u = t; u < 1024; u += 512) {
        int e = u >> 3, dz = u & 7;
        float2 vv = mesh[rb + (size_t)e * ZP + dz];
        tre[dz][e] = vv.x; tim[dz][e] = vv.y;
    }
    __syncthreads();
    const int w = t >> 6, lane = t & 63;
    float r0 = tre[w][lane],      i0 = tim[w][lane];
    float r1 = tre[w][lane + 64], i1 = tim[w][lane + 64];
    wfft_dif_fwd(r0, i0, r1, i1, lane);
    tre[w][lane] = r0;      tim[w][lane] = i0;
    tre[w][lane + 64] = r1; tim[w][lane + 64] = i1;
    __syncthreads();
    for (int u = t; u < 1024; u += 512) {
        int e = u >> 3, dz = u & 7;
        mesh[rb + (size_t)e * ZP + dz] = make_float2(tre[dz][e], tim[dz][e]);
    }
}

// ---------- fused x: DIF fwd -> G(k) at rev-indexed k -> DIT inv ----------

__global__ __launch_bounds__(512) void fftXGw(float2* __restrict__ mesh,
                                              const float* __restrict__ cell) {
    __shared__ float tre[8][132], tim[8][132];
    const int t = threadIdx.x, b = blockIdx.x;
    const int py = b & 127, zf0 = (b >> 7) << 3;
    for (int u = t; u < 1024; u += 512) {
        int e = u >> 3, dz = u & 7;
        float2 vv = mesh[(size_t)((e << 7) | py) * ZP + zf0 + dz];
        tre[dz][e] = vv.x; tim[dz][e] = vv.y;
    }
    __syncthreads();
    const int w = t >> 6, lane = t & 63;
    float r0 = tre[w][lane],      i0 = tim[w][lane];
    float r1 = tre[w][lane + 64], i1 = tim[w][lane + 64];
    wfft_dif_fwd(r0, i0, r1, i1, lane);
    {
        float inv[9]; float det; inv3x3(cell, inv, &det);
        float invVol = 1.0f / fabsf(det);
        int my = (int)(__brev((unsigned)py) >> 25);
        int mz = zf0 + w;
        float fy = (my < 64) ? (float)my : (float)(my - 128);
        float fz = (mz < 64) ? (float)mz : (float)(mz - 128);
        int mx0 = (int)(__brev((unsigned)lane) >> 25);
        #pragma unroll
        for (int s = 0; s < 2; ++s) {
            int mx = mx0 + s;
            float fx = (mx < 64) ? (float)mx : (float)(mx - 128);
            float kx = TWO_PI_F * (fx * inv[0] + fy * inv[1] + fz * inv[2]);
            float ky = TWO_PI_F * (fx * inv[3] + fy * inv[4] + fz * inv[5]);
            float kz = TWO_PI_F * (fx * inv[6] + fy * inv[7] + fz * inv[8]);
            float ksq = kx * kx + ky * ky + kz * kz;
            float G = (ksq == 0.0f) ? 0.0f
                      : FOUR_PI_F / ksq * __expf(-0.5f * ksq) * invVol;
            if (s == 0) { r0 *= G; i0 *= G; } else { r1 *= G; i1 *= G; }
        }
    }
    wfft_dit_inv(r0, i0, r1, i1, lane);
    tre[w][lane] = r0;      tim[w][lane] = i0;
    tre[w][lane + 64] = r1; tim[w][lane + 64] = i1;
    __syncthreads();
    for (int u = t; u < 1024; u += 512) {
        int e = u >> 3, dz = u & 7;
        mesh[(size_t)((e << 7) | py) * ZP + zf0 + dz] =
            make_float2(tre[dz][e], tim[dz][e]);
    }
}

// ---------- y inverse: bit-reversed positions in -> natural out ----------

__global__ __launch_bounds__(512) void fftYinv(float2* __restrict__ mesh) {
    __shared__ float tre[8][132], tim[8][132];
    const int t = threadIdx.x, b = blockIdx.x;
    const int x = b & 127, zf0 = (b >> 7) << 3;
    const size_t rb = ((size_t)(x << 7)) * ZP + zf0;
    for (int u = t; u < 1024; u += 512) {
        int e = u >> 3, dz = u & 7;
        float2 vv = mesh[rb + (size_t)e * ZP + dz];
        tre[dz][e] = vv.x; tim[dz][e] = vv.y;
    }
    __syncthreads();
    const int w = t >> 6, lane = t & 63;
    float r0 = tre[w][lane],      i0 = tim[w][lane];
    float r1 = tre[w][lane + 64], i1 = tim[w][lane + 64];
    wfft_dit_inv(r0, i0, r1, i1, lane);
    tre[w][lane] = r0;      tim[w][lane] = i0;
    tre[w][lane + 64] = r1; tim[w][lane + 64] = i1;
    __syncthreads();
    for (int u = t; u < 1024; u += 512) {
        int e = u >> 3, dz = u & 7;
        mesh[rb + (size_t)e * ZP + dz] = make_float2(tre[dz][e], tim[dz][e]);
    }
}

// ---------- z inverse: Hermitian mirror -> real out ----------

__global__ __launch_bounds__(1024) void fftZinv(const float2* __restrict__ mesh,
                                                float* __restrict__ rout) {
    __shared__ float tre[16][132], tim[16][132];
    const int t = threadIdx.x, b = blockIdx.x;
    for (int u = t; u < 2048; u += 1024) {
        int l = u >> 7, e = u & 127;
        int src = (e <= 64) ? e : 128 - e;
        float2 vv = mesh[(size_t)((b << 4) | l) * ZP + src];
        tre[l][e] = vv.x;
        tim[l][e] = (e <= 64) ? vv.y : -vv.y;
    }
    __syncthreads();
    const int w = t >> 6, lane = t & 63;
    int e0 = (int)(__brev((unsigned)lane) >> 25);
    float r0 = tre[w][e0],     i0 = tim[w][e0];
    float r1 = tre[w][e0 + 1], i1 = tim[w][e0 + 1];
    wfft_dit_inv(r0, i0, r1, i1, lane);
    const size_t rb = ((size_t)((b << 4) | w) << 7);
    rout[rb + lane] = r0;
    rout[rb + lane + 64] = r1;
}

// ---------- gather ----------

__global__ void gather_kernel(const float4* __restrict__ sorted, const int* __restrict__ sortedIdx,
                              const float* __restrict__ rmesh, float* __restrict__ out, int n) {
    int t = blockIdx.x * blockDim.x + threadIdx.x;
    if (t >= n) return;
    float4 a = sorted[t];
    float wx[4], wy[4], wz[4];
    int ix[4], iy[4], iz[4];
    {
        float fl = floorf(a.x); int i0 = (int)fl; float x = a.x - fl - 0.5f; w4(x, wx);
        #pragma unroll
        for (int s = 0; s < 4; ++s) ix[s] = (i0 + s - 1) & 127;
    }
    {
        float fl = floorf(a.y); int i0 = (int)fl; float x = a.y - fl - 0.5f; w4(x, wy);
        #pragma unroll
        for (int s = 0; s < 4; ++s) iy[s] = (i0 + s - 1) & 127;
    }
    {
        float fl = floorf(a.z); int i0 = (int)fl; float x = a.z - fl - 0.5f; w4(x, wz);
        #pragma unroll
        for (int s = 0; s < 4; ++s) iz[s] = (i0 + s - 1) & 127;
    }
    float sum = 0.0f;
    #pragma unroll
    for (int i = 0; i < 4; ++i) {
        int bx = ix[i] << 14;
        float acc_i = 0.0f;
        #pragma unroll
        for (int j = 0; j < 4; ++j) {
            int bxy = bx | (iy[j] << 7);
            float acc_j = 0.0f;
            #pragma unroll
            for (int k = 0; k < 4; ++k) {
                acc_j += wz[k] * rmesh[bxy | iz[k]];
            }
            acc_i += wy[j] * acc_j;
        }
        sum += wx[i] * acc_i;
    }
    out[sortedIdx[t]] = sum - a.w * 0.79788456080286535588f;
}

// ---------- launch ----------

extern "C" void kernel_launch(void* const* d_in, const int* in_sizes, int n_in,
                              void* d_out, int out_size, void* d_ws, size_t ws_size,
                              hipStream_t stream) {
    const float* cell = (const float*)d_in[0];
    const float* pos  = (const float*)d_in[1];
    const float* q    = (const float*)d_in[2];
    float* out = (float*)d_out;
    const int n = in_sizes[2];

    char* ws = (char*)d_ws;
    size_t o = 0;
    float4* sorted   = (float4*)(ws + o); o += (size_t)n * 16;
    int* sortedIdx   = (int*)(ws + o);    o += (size_t)n * 4;  o = (o + 255) & ~(size_t)255;
    int* hist        = (int*)(ws + o);    o += (size_t)BINS * 4;            // also reorder cursor
    int* offsets     = (int*)(ws + o);    o += (size_t)(BINS + 4) * 4;
    int* partials    = (int*)(ws + o);    o += (size_t)SCAN_BLOCKS * 4; o = (o + 255) & ~(size_t)255;
    float2* mesh     = (float2*)(ws + o); o += (size_t)128 * 128 * ZP * 8;  // 9.4 MB
    float* rmesh     = (float*)(ws + o);  // NTOT * 4 = 8 MB

    zero_int_kernel<<<BINS / 256, 256, 0, stream>>>(hist, BINS);
    hist_kernel<<<(n + 255) / 256, 256, 0, stream>>>(cell, pos, hist, n);
    scan_local<<<SCAN_BLOCKS, 256, 0, stream>>>((const int4*)hist, (int4*)offsets, partials);
    scan_add<<<SCAN_BLOCKS, 256, 0, stream>>>((int4*)hist, (int4*)offsets, partials, offsets);
    reorder_kernel<<<(n + 255) / 256, 256, 0, stream>>>(cell, pos, q, hist, sorted, sortedIdx, n);

    column_scatter_kernel<<<1024, 512, 0, stream>>>(sorted, offsets, rmesh);

    fftZfwd<<<1024, 1024, 0, stream>>>(rmesh, mesh);
    fftYfwd<<<9 * 128, 512, 0, stream>>>(mesh);
    fftXGw<<<9 * 128, 512, 0, stream>>>(mesh, cell);
    fftYinv<<<9 * 128, 512, 0, stream>>>(mesh);
    fftZinv<<<1024, 1024, 0, stream>>>(mesh, rmesh);

    gather_kernel<<<(n + 255) / 256, 256, 0, stream>>>(sorted, sortedIdx, rmesh, out, n);
}

// Round 10
// 162.546 us; speedup vs baseline: 1.2196x; 1.0092x over previous
//
#include <hip/hip_runtime.h>
#include <math.h>

#define NTOT (128*128*128)
#define NBIN2 64                 // bins per axis (2 cells per bin)
#define BINS (NBIN2*NBIN2*NBIN2) // 262144
#define SCAN_BLOCKS 256

#define ZP 72                    // complex-mesh z pitch (>= 65, mult of 8)

#define PI_F      3.14159265358979323846f
#define TWO_PI_F  6.28318530717958647692f
#define FOUR_PI_F 12.5663706143591729539f

// ---------- helpers ----------

__device__ inline void inv3x3(const float* __restrict__ c, float* inv, float* detOut) {
    float a = c[0], b = c[1], cc = c[2];
    float d = c[3], e = c[4], f  = c[5];
    float g = c[6], h = c[7], i  = c[8];
    float A = e * i - f * h;
    float B = f * g - d * i;
    float C = d * h - e * g;
    float det = a * A + b * B + cc * C;
    float r = 1.0f / det;
    inv[0] = A * r;              inv[1] = (cc * h - b * i) * r;  inv[2] = (b * f - cc * e) * r;
    inv[3] = B * r;              inv[4] = (a * i - cc * g) * r;  inv[5] = (cc * d - a * f) * r;
    inv[6] = C * r;              inv[7] = (b * g - a * h) * r;   inv[8] = (a * e - b * d) * r;
    *detOut = det;
}

__device__ inline void w4(float x, float* w) {
    float x2 = x * x, x3 = x2 * x;
    w[0] = (1.0f  - 6.0f  * x + 12.0f * x2 - 8.0f  * x3) * (1.0f / 48.0f);
    w[1] = (23.0f - 30.0f * x - 12.0f * x2 + 24.0f * x3) * (1.0f / 48.0f);
    w[2] = (23.0f + 30.0f * x - 12.0f * x2 - 24.0f * x3) * (1.0f / 48.0f);
    w[3] = (1.0f  + 6.0f  * x + 12.0f * x2 + 8.0f  * x3) * (1.0f / 48.0f);
}

__device__ inline void atom_rel(const float* __restrict__ cell,
                                const float* __restrict__ pos, int t,
                                float* rx, float* ry, float* rz) {
    float inv[9]; float det;
    inv3x3(cell, inv, &det);
    float px = pos[3 * t], py = pos[3 * t + 1], pz = pos[3 * t + 2];
    *rx = (px * inv[0] + py * inv[3] + pz * inv[6]) * 128.0f;
    *ry = (px * inv[1] + py * inv[4] + pz * inv[7]) * 128.0f;
    *rz = (px * inv[2] + py * inv[5] + pz * inv[8]) * 128.0f;
}

__device__ inline int bin_of(float rx, float ry, float rz) {
    int ix = ((int)floorf(rx)) & 127;
    int iy = ((int)floorf(ry)) & 127;
    int iz = ((int)floorf(rz)) & 127;
    return ((((ix >> 1) << 6) | (iy >> 1)) << 6) | (iz >> 1);
}

// periodic wrap of a cell-units offset into (-64, 64]
__device__ inline float wrap128(float u) {
    u = (u > 64.0f) ? u - 128.0f : u;
    u = (u < -64.0f) ? u + 128.0f : u;
    return u;
}

// cubic B-spline M4 assignment weight (unnormalized: true weight = this / 6)
__device__ inline float bspline(float u) {
    float a = fabsf(u);
    float t = fmaxf(2.0f - a, 0.0f);
    float s = fmaxf(1.0f - a, 0.0f);
    return t * t * t - 4.0f * s * s * s;
}

// ---------- binning ----------

__global__ void zero_int_kernel(int* __restrict__ p, int n) {
    int i = blockIdx.x * blockDim.x + threadIdx.x;
    if (i < n) p[i] = 0;
}

__global__ void hist_kernel(const float* __restrict__ cell, const float* __restrict__ pos,
                            int* __restrict__ hist, int n) {
    int t = blockIdx.x * blockDim.x + threadIdx.x;
    if (t >= n) return;
    float rx, ry, rz;
    atom_rel(cell, pos, t, &rx, &ry, &rz);
    atomicAdd(&hist[bin_of(rx, ry, rz)], 1);
}

__global__ __launch_bounds__(256) void scan_local(const int4* __restrict__ hist4,
                                                  int4* __restrict__ off4,
                                                  int* __restrict__ partials) {
    const int b = blockIdx.x, t = threadIdx.x;
    const int idx = b * 256 + t;
    int4 h = hist4[idx];
    int s = h.x + h.y + h.z + h.w;
    int lane = t & 63, wv = t >> 6;
    int v = s;
    #pragma unroll
    for (int d = 1; d < 64; d <<= 1) {
        int o = __shfl_up(v, d, 64);
        if (lane >= d) v += o;
    }
    __shared__ int wsum[4];
    if (lane == 63) wsum[wv] = v;
    __syncthreads();
    int add = 0;
    #pragma unroll
    for (int k = 0; k < 4; ++k) if (k < wv) add += wsum[k];
    int run = add + v - s;
    int4 o4;
    o4.x = run; run += h.x;
    o4.y = run; run += h.y;
    o4.z = run; run += h.z;
    o4.w = run; run += h.w;
    off4[idx] = o4;
    if (t == 255) partials[b] = run;
}

__global__ __launch_bounds__(256) void scan_add(int4* __restrict__ hist4,
                                                int4* __restrict__ off4,
                                                const int* __restrict__ partials,
                                                int* __restrict__ offsets) {
    const int b = blockIdx.x, t = threadIdx.x;
    int lane = t & 63, wv = t >> 6;
    int v = (t < b) ? partials[t] : 0;
    #pragma unroll
    for (int d = 32; d >= 1; d >>= 1) v += __shfl_xor(v, d, 64);
    __shared__ int ws2[4];
    __shared__ int base_s;
    if (lane == 0) ws2[wv] = v;
    __syncthreads();
    if (t == 0) base_s = ws2[0] + ws2[1] + ws2[2] + ws2[3];
    __syncthreads();
    const int base = base_s;
    const int idx = b * 256 + t;
    int4 o4 = off4[idx];
    o4.x += base; o4.y += base; o4.z += base; o4.w += base;
    off4[idx]  = o4;
    hist4[idx] = o4;
    if (b == SCAN_BLOCKS - 1 && t == 255) offsets[BINS] = base + partials[b];
}

__global__ void reorder_kernel(const float* __restrict__ cell, const float* __restrict__ pos,
                               const float* __restrict__ q, int* __restrict__ cursor,
                               float4* __restrict__ sorted, int* __restrict__ sortedIdx, int n) {
    int t = blockIdx.x * blockDim.x + threadIdx.x;
    if (t >= n) return;
    float rx, ry, rz;
    atom_rel(cell, pos, t, &rx, &ry, &rz);
    int p = atomicAdd(&cursor[bin_of(rx, ry, rz)], 1);
    sorted[p] = make_float4(rx, ry, rz, q[t]);
    sortedIdx[p] = t;
}

// ---------- quad scatter: thread owns 2x2 xy columns x 4 z-cells (16 cells) ----------
// Register accumulators, no atomics, no LDS; speculative next-atom prefetch.

__global__ __launch_bounds__(256) void quad_scatter_kernel(const float4* __restrict__ atoms,
                                                           const int* __restrict__ offsets,
                                                           float* __restrict__ rmesh, int n) {
    const int tid = blockIdx.x * 256 + threadIdx.x;   // 131072 threads
    const int zq = tid & 31;                          // z-quad (low bits: lanes share xy bins)
    const int gy = (tid >> 5) & 63;
    const int gx = tid >> 11;
    const int cx0 = gx << 1, cy0 = gy << 1, cz0 = zq << 2;

    float acc[2][2][4];
    #pragma unroll
    for (int a2 = 0; a2 < 2; ++a2)
        #pragma unroll
        for (int b2 = 0; b2 < 2; ++b2)
            #pragma unroll
            for (int k = 0; k < 4; ++k) acc[a2][b2][k] = 0.0f;

    const float fcx = (float)cx0, fcy = (float)cy0, fcz = (float)cz0;

    // x cells [cx0-2, cx0+2] -> 3 bins; y same; z cells [cz0-2, cz0+5] -> exactly 4 bins
    const int xb0 = ((cx0 - 2) & 127) >> 1;
    const int yb0 = ((cy0 - 2) & 127) >> 1;
    const int zb0 = ((cz0 - 2) & 127) >> 1;
    int len0 = 64 - zb0; if (len0 > 4) len0 = 4;
    const int len1 = 4 - len0;

    // flat ranges: r in [0,18): xy = r>>1 (dx=xy/3, dy=xy%3), half = r&1
    int r = -1, i = 0, e = 0;
    // advance to first non-empty range
    while (i >= e) {
        if (++r >= 18) break;
        int half = r & 1;
        if (half == 1 && len1 == 0) continue;
        int xy = r >> 1;
        int dx = xy / 3, dy = xy - dx * 3;
        int bx = (xb0 + dx) & 63;
        int by = (yb0 + dy) & 63;
        int binBase = ((bx << 6) | by) << 6;
        if (half == 0) { i = offsets[binBase + zb0]; e = offsets[binBase + zb0 + len0]; }
        else           { i = offsets[binBase];       e = offsets[binBase + len1]; }
    }

    if (r < 18) {
        float4 a = atoms[i];
        for (;;) {
            // speculative prefetch of the next atom in this range (dup if at end)
            float4 aspec = atoms[(i + 1 < e) ? (i + 1) : i];

            // compute with a
            float ux = wrap128(a.x - fcx);
            float wx0 = bspline(ux);
            float wx1 = bspline(ux - 1.0f);
            float uy = wrap128(a.y - fcy);
            float wy0 = bspline(uy);
            float wy1 = bspline(uy - 1.0f);
            float uz = wrap128(a.z - fcz);
            float wz0 = bspline(uz);
            float wz1 = bspline(uz - 1.0f);
            float wz2 = bspline(uz - 2.0f);
            float wz3 = bspline(uz - 3.0f);
            float qs = a.w * (1.0f / 216.0f);
            float qx0 = qs * wx0, qx1 = qs * wx1;
            float m00 = qx0 * wy0, m01 = qx0 * wy1;
            float m10 = qx1 * wy0, m11 = qx1 * wy1;
            acc[0][0][0] += m00 * wz0; acc[0][0][1] += m00 * wz1;
            acc[0][0][2] += m00 * wz2; acc[0][0][3] += m00 * wz3;
            acc[0][1][0] += m01 * wz0; acc[0][1][1] += m01 * wz1;
            acc[0][1][2] += m01 * wz2; acc[0][1][3] += m01 * wz3;
            acc[1][0][0] += m10 * wz0; acc[1][0][1] += m10 * wz1;
            acc[1][0][2] += m10 * wz2; acc[1][0][3] += m10 * wz3;
            acc[1][1][0] += m11 * wz0; acc[1][1][1] += m11 * wz1;
            acc[1][1][2] += m11 * wz2; acc[1][1][3] += m11 * wz3;

            ++i;
            if (i < e) {
                a = aspec;
            } else {
                while (i >= e) {
                    if (++r >= 18) break;
                    int half = r & 1;
                    if (half == 1 && len1 == 0) continue;
                    int xy = r >> 1;
                    int dx = xy / 3, dy = xy - dx * 3;
                    int bx = (xb0 + dx) & 63;
                    int by = (yb0 + dy) & 63;
                    int binBase = ((bx << 6) | by) << 6;
                    if (half == 0) { i = offsets[binBase + zb0]; e = offsets[binBase + zb0 + len0]; }
                    else           { i = offsets[binBase];       e = offsets[binBase + len1]; }
                }
                if (r >= 18) break;
                a = atoms[i];
            }
        }
    }

    #pragma unroll
    for (int a2 = 0; a2 < 2; ++a2) {
        #pragma unroll
        for (int b2 = 0; b2 < 2; ++b2) {
            const size_t base = ((size_t)(cx0 + a2) << 14) | ((size_t)(cy0 + b2) << 7) | (size_t)cz0;
            *(float4*)&rmesh[base] = make_float4(acc[a2][b2][0], acc[a2][b2][1],
                                                 acc[a2][b2][2], acc[a2][b2][3]);
        }
    }
}

// ---------- register-shuffle 128-pt FFT (wave per line) ----------

__device__ inline void bfly_dif(float& rr, float& ii, int h, bool hi, float cs, float sn) {
    float pr = __shfl_xor(rr, h), pi = __shfl_xor(ii, h);
    float br = hi ? (pr - rr) : (rr + pr);
    float bi = hi ? (pi - ii) : (ii + pi);
    rr = cs * br - sn * bi;
    ii = cs * bi + sn * br;
}

__device__ inline void bfly_dit(float& rr, float& ii, int h, bool hi, float cs, float sn) {
    float pr = __shfl_xor(rr, h), pi = __shfl_xor(ii, h);
    float xr = hi ? rr : pr, xi = hi ? ii : pi;
    float br = hi ? pr : rr, bi = hi ? pi : ii;
    float tr = cs * xr - sn * xi, ti = cs * xi + sn * xr;
    rr = hi ? (br - tr) : (br + tr);
    ii = hi ? (bi - ti) : (bi + ti);
}

__device__ inline void wfft_dif_fwd(float& r0, float& i0, float& r1, float& i1, int lane) {
    {
        float ang = -PI_F * (float)lane * (1.0f / 64.0f);
        float sn, cs; __sincosf(ang, &sn, &cs);
        float ar = r0 + r1, ai = i0 + i1;
        float dr = r0 - r1, di = i0 - i1;
        r0 = ar; i0 = ai;
        r1 = cs * dr - sn * di;
        i1 = cs * di + sn * dr;
    }
    #pragma unroll
    for (int h = 32; h >= 1; h >>= 1) {
        int pos = lane & (h - 1);
        bool hi = (lane & h) != 0;
        float ang = hi ? (-PI_F * (float)pos / (float)h) : 0.0f;
        float sn, cs; __sincosf(ang, &sn, &cs);
        bfly_dif(r0, i0, h, hi, cs, sn);
        bfly_dif(r1, i1, h, hi, cs, sn);
    }
}

__device__ inline void wfft_dit_inv(float& r0, float& i0, float& r1, float& i1, int lane) {
    #pragma unroll
    for (int h = 1; h <= 32; h <<= 1) {
        int pos = lane & (h - 1);
        bool hi = (lane & h) != 0;
        float ang = PI_F * (float)pos / (float)h;
        float sn, cs; __sincosf(ang, &sn, &cs);
        bfly_dit(r0, i0, h, hi, cs, sn);
        bfly_dit(r1, i1, h, hi, cs, sn);
    }
    {
        float ang = PI_F * (float)lane * (1.0f / 64.0f);
        float sn, cs; __sincosf(ang, &sn, &cs);
        float tr = cs * r1 - sn * i1, ti = cs * i1 + sn * r1;
        float nr = r0 + tr, ni = i0 + ti;
        r1 = r0 - tr; i1 = i0 - ti;
        r0 = nr; i0 = ni;
    }
}

// ---------- z forward: real -> complex natural order (Hermitian prefix) ----------

__global__ __launch_bounds__(1024) void fftZfwd(const float* __restrict__ rin,
                                                float2* __restrict__ mesh) {
    __shared__ float tre[16][132], tim[16][132];
    const int t = threadIdx.x, b = blockIdx.x;
    for (int u = t; u < 2048; u += 1024) {
        int l = u >> 7, e = u & 127;
        tre[l][e] = rin[((size_t)((b << 4) | l) << 7) + e];
    }
    __syncthreads();
    const int w = t >> 6, lane = t & 63;
    float r0 = tre[w][lane],      i0 = 0.0f;
    float r1 = tre[w][lane + 64], i1 = 0.0f;
    wfft_dif_fwd(r0, i0, r1, i1, lane);
    int e0 = (int)(__brev((unsigned)lane) >> 25);
    tre[w][e0] = r0;     tim[w][e0] = i0;
    tre[w][e0 + 1] = r1; tim[w][e0 + 1] = i1;
    __syncthreads();
    for (int u = t; u < 2048; u += 1024) {
        int l = u >> 7, e = u & 127;
        if (e < ZP)
            mesh[(size_t)((b << 4) | l) * ZP + e] = make_float2(tre[l][e], tim[l][e]);
    }
}

// ---------- y forward: natural in -> bit-reversed positions ----------

__global__ __launch_bounds__(512) void fftYfwd(float2* __restrict__ mesh) {
    __shared__ float tre[8][132], tim[8][132];
    const int t = threadIdx.x, b = blockIdx.x;
    const int x = b & 127, zf0 = (b >> 7) << 3;
    const size_t rb = ((size_t)(x << 7)) * ZP + zf0;
    for (int u = t; u < 1024; u += 512) {
        int e = u >> 3, dz = u & 7;
        float2 vv = mesh[rb + (size_t)e * ZP + dz];
        tre[dz][e] = vv.x; tim[dz][e] = vv.y;
    }
    __syncthreads();
    const int w = t >> 6, lane = t & 63;
    float r0 = tre[w][lane],      i0 = tim[w][lane];
    float r1 = tre[w][lane + 64], i1 = tim[w][lane + 64];
    wfft_dif_fwd(r0, i0, r1, i1, lane);
    tre[w][lane] = r0;      tim[w][lane] = i0;
    tre[w][lane + 64] = r1; tim[w][lane + 64] = i1;
    __syncthreads();
    for (int u = t; u < 1024; u += 512) {
        int e = u >> 3, dz = u & 7;
        mesh[rb + (size_t)e * ZP + dz] = make_float2(tre[dz][e], tim[dz][e]);
    }
}

// ---------- fused x: DIF fwd -> G(k) at rev-indexed k -> DIT inv ----------

__global__ __launch_bounds__(512) void fftXGw(float2* __restrict__ mesh,
                                              const float* __restrict__ cell) {
    __shared__ float tre[8][132], tim[8][132];
    const int t = threadIdx.x, b = blockIdx.x;
    const int py = b & 127, zf0 = (b >> 7) << 3;
    for (int u = t; u < 1024; u += 512) {
        int e = u >> 3, dz = u & 7;
        float2 vv = mesh[(size_t)((e << 7) | py) * ZP + zf0 + dz];
        tre[dz][e] = vv.x; tim[dz][e] = vv.y;
    }
    __syncthreads();
    const int w = t >> 6, lane = t & 63;
    float r0 = tre[w][lane],      i0 = tim[w][lane];
    float r1 = tre[w][lane + 64], i1 = tim[w][lane + 64];
    wfft_dif_fwd(r0, i0, r1, i1, lane);
    {
        float inv[9]; float det; inv3x3(cell, inv, &det);
        float invVol = 1.0f / fabsf(det);
        int my = (int)(__brev((unsigned)py) >> 25);
        int mz = zf0 + w;
        float fy = (my < 64) ? (float)my : (float)(my - 128);
        float fz = (mz < 64) ? (float)mz : (float)(mz - 128);
        int mx0 = (int)(__brev((unsigned)lane) >> 25);
        #pragma unroll
        for (int s = 0; s < 2; ++s) {
            int mx = mx0 + s;
            float fx = (mx < 64) ? (float)mx : (float)(mx - 128);
            float kx = TWO_PI_F * (fx * inv[0] + fy * inv[1] + fz * inv[2]);
            float ky = TWO_PI_F * (fx * inv[3] + fy * inv[4] + fz * inv[5]);
            float kz = TWO_PI_F * (fx * inv[6] + fy * inv[7] + fz * inv[8]);
            float ksq = kx * kx + ky * ky + kz * kz;
            float G = (ksq == 0.0f) ? 0.0f
                      : FOUR_PI_F / ksq * __expf(-0.5f * ksq) * invVol;
            if (s == 0) { r0 *= G; i0 *= G; } else { r1 *= G; i1 *= G; }
        }
    }
    wfft_dit_inv(r0, i0, r1, i1, lane);
    tre[w][lane] = r0;      tim[w][lane] = i0;
    tre[w][lane + 64] = r1; tim[w][lane + 64] = i1;
    __syncthreads();
    for (int u = t; u < 1024; u += 512) {
        int e = u >> 3, dz = u & 7;
        mesh[(size_t)((e << 7) | py) * ZP + zf0 + dz] =
            make_float2(tre[dz][e], tim[dz][e]);
    }
}

// ---------- y inverse: bit-reversed positions in -> natural out ----------

__global__ __launch_bounds__(512) void fftYinv(float2* __restrict__ mesh) {
    __shared__ float tre[8][132], tim[8][132];
    const int t = threadIdx.x, b = blockIdx.x;
    const int x = b & 127, zf0 = (b >> 7) << 3;
    const size_t rb = ((size_t)(x << 7)) * ZP + zf0;
    for (int u = t; u < 1024; u += 512) {
        int e = u >> 3, dz = u & 7;
        float2 vv = mesh[rb + (size_t)e * ZP + dz];
        tre[dz][e] = vv.x; tim[dz][e] = vv.y;
    }
    __syncthreads();
    const int w = t >> 6, lane = t & 63;
    float r0 = tre[w][lane],      i0 = tim[w][lane];
    float r1 = tre[w][lane + 64], i1 = tim[w][lane + 64];
    wfft_dit_inv(r0, i0, r1, i1, lane);
    tre[w][lane] = r0;      tim[w][lane] = i0;
    tre[w][lane + 64] = r1; tim[w][lane + 64] = i1;
    __syncthreads();
    for (int u = t; u < 1024; u += 512) {
        int e = u >> 3, dz = u & 7;
        mesh[rb + (size_t)e * ZP + dz] = make_float2(tre[dz][e], tim[dz][e]);
    }
}

// ---------- z inverse: Hermitian mirror -> real out ----------

__global__ __launch_bounds__(1024) void fftZinv(const float2* __restrict__ mesh,
                                                float* __restrict__ rout) {
    __shared__ float tre[16][132], tim[16][132];
    const int t = threadIdx.x, b = blockIdx.x;
    for (int u = t; u < 2048; u += 1024) {
        int l = u >> 7, e = u & 127;
        int src = (e <= 64) ? e : 128 - e;
        float2 vv = mesh[(size_t)((b << 4) | l) * ZP + src];
        tre[l][e] = vv.x;
        tim[l][e] = (e <= 64) ? vv.y : -vv.y;
    }
    __syncthreads();
    const int w = t >> 6, lane = t & 63;
    int e0 = (int)(__brev((unsigned)lane) >> 25);
    float r0 = tre[w][e0],     i0 = tim[w][e0];
    float r1 = tre[w][e0 + 1], i1 = tim[w][e0 + 1];
    wfft_dit_inv(r0, i0, r1, i1, lane);
    const size_t rb = ((size_t)((b << 4) | w) << 7);
    rout[rb + lane] = r0;
    rout[rb + lane + 64] = r1;
}

// ---------- gather ----------

__global__ void gather_kernel(const float4* __restrict__ sorted, const int* __restrict__ sortedIdx,
                              const float* __restrict__ rmesh, float* __restrict__ out, int n) {
    int t = blockIdx.x * blockDim.x + threadIdx.x;
    if (t >= n) return;
    float4 a = sorted[t];
    float wx[4], wy[4], wz[4];
    int ix[4], iy[4], iz[4];
    {
        float fl = floorf(a.x); int i0 = (int)fl; float x = a.x - fl - 0.5f; w4(x, wx);
        #pragma unroll
        for (int s = 0; s < 4; ++s) ix[s] = (i0 + s - 1) & 127;
    }
    {
        float fl = floorf(a.y); int i0 = (int)fl; float x = a.y - fl - 0.5f; w4(x, wy);
        #pragma unroll
        for (int s = 0; s < 4; ++s) iy[s] = (i0 + s - 1) & 127;
    }
    {
        float fl = floorf(a.z); int i0 = (int)fl; float x = a.z - fl - 0.5f; w4(x, wz);
        #pragma unroll
        for (int s = 0; s < 4; ++s) iz[s] = (i0 + s - 1) & 127;
    }
    float sum = 0.0f;
    #pragma unroll
    for (int i = 0; i < 4; ++i) {
        int bx = ix[i] << 14;
        float acc_i = 0.0f;
        #pragma unroll
        for (int j = 0; j < 4; ++j) {
            int bxy = bx | (iy[j] << 7);
            float acc_j = 0.0f;
            #pragma unroll
            for (int k = 0; k < 4; ++k) {
                acc_j += wz[k] * rmesh[bxy | iz[k]];
            }
            acc_i += wy[j] * acc_j;
        }
        sum += wx[i] * acc_i;
    }
    out[sortedIdx[t]] = sum - a.w * 0.79788456080286535588f;
}

// ---------- launch ----------

extern "C" void kernel_launch(void* const* d_in, const int* in_sizes, int n_in,
                              void* d_out, int out_size, void* d_ws, size_t ws_size,
                              hipStream_t stream) {
    const float* cell = (const float*)d_in[0];
    const float* pos  = (const float*)d_in[1];
    const float* q    = (const float*)d_in[2];
    float* out = (float*)d_out;
    const int n = in_sizes[2];

    char* ws = (char*)d_ws;
    size_t o = 0;
    float4* sorted   = (float4*)(ws + o); o += (size_t)n * 16;
    int* sortedIdx   = (int*)(ws + o);    o += (size_t)n * 4;  o = (o + 255) & ~(size_t)255;
    int* hist        = (int*)(ws + o);    o += (size_t)BINS * 4;            // also reorder cursor
    int* offsets     = (int*)(ws + o);    o += (size_t)(BINS + 4) * 4;
    int* partials    = (int*)(ws + o);    o += (size_t)SCAN_BLOCKS * 4; o = (o + 255) & ~(size_t)255;
    float2* mesh     = (float2*)(ws + o); o += (size_t)128 * 128 * ZP * 8;  // 9.4 MB
    float* rmesh     = (float*)(ws + o);  // NTOT * 4 = 8 MB

    zero_int_kernel<<<BINS / 256, 256, 0, stream>>>(hist, BINS);
    hist_kernel<<<(n + 255) / 256, 256, 0, stream>>>(cell, pos, hist, n);
    scan_local<<<SCAN_BLOCKS, 256, 0, stream>>>((const int4*)hist, (int4*)offsets, partials);
    scan_add<<<SCAN_BLOCKS, 256, 0, stream>>>((int4*)hist, (int4*)offsets, partials, offsets);
    reorder_kernel<<<(n + 255) / 256, 256, 0, stream>>>(cell, pos, q, hist, sorted, sortedIdx, n);

    quad_scatter_kernel<<<512, 256, 0, stream>>>(sorted, offsets, rmesh, n);

    fftZfwd<<<1024, 1024, 0, stream>>>(rmesh, mesh);
    fftYfwd<<<9 * 128, 512, 0, stream>>>(mesh);
    fftXGw<<<9 * 128, 512, 0, stream>>>(mesh, cell);
    fftYinv<<<9 * 128, 512, 0, stream>>>(mesh);
    fftZinv<<<1024, 1024, 0, stream>>>(mesh, rmesh);

    gather_kernel<<<(n + 255) / 256, 256, 0, stream>>>(sorted, sortedIdx, rmesh, out, n);
}